// Round 6
// baseline (284.275 us; speedup 1.0000x reference)
//
#include <hip/hip_runtime.h>
#include <math.h>

#define T_DIM 8192
#define B_DIM 4
#define INDIM 512
#define DV 512
#define DK 64
#define CHUNK 128
#define NCH (T_DIM / CHUNK)     // 64
#define ROWS (T_DIM * B_DIM)    // 32768
#define NPAD 768                // 704 proj cols padded to 6x128
#define KCAT 192                // 128 intra + 64 state
#define EPSF 1e-8f

typedef float float4_t __attribute__((ext_vector_type(4)));
typedef short short8_t __attribute__((ext_vector_type(8)));
typedef _Float16 half8_t __attribute__((ext_vector_type(8)));

__device__ inline unsigned short f2bf(float f) {
  unsigned int u = __float_as_uint(f);
  unsigned int r = (u + 0x7fffu + ((u >> 16) & 1u)) >> 16;
  return (unsigned short)r;
}
__device__ inline float bf2f(unsigned short h) {
  return __uint_as_float(((unsigned int)h) << 16);
}
__device__ inline unsigned short f2h(float f) {
  _Float16 h = (_Float16)f;
  unsigned short u;
  __builtin_memcpy(&u, &h, 2);
  return u;
}

__device__ inline void gload16(const void* g, void* l) {
  __builtin_amdgcn_global_load_lds(
      (const __attribute__((address_space(1))) void*)g,
      (__attribute__((address_space(3))) void*)l, 16, 0, 0);
}

// ---------------------------------------------------------------------------
// C0: weight cast only (x is now consumed fp32 directly by proj).
// 384 blocks: padded concat weights -> wh (fp16) + bcat.
// ---------------------------------------------------------------------------
__global__ __launch_bounds__(256) void wcast_kernel(
    const float* __restrict__ Wv, const float* __restrict__ Wk,
    const float* __restrict__ Wq, const float* __restrict__ Wa,
    const float* __restrict__ bv, const float* __restrict__ bk,
    const float* __restrict__ bq, const float* __restrict__ ba,
    unsigned short* __restrict__ wh, float* __restrict__ bcat)
{
  const int t = blockIdx.x * 256 + threadIdx.x;
  const size_t i4 = (size_t)t * 4;
  const int row = (int)(i4 >> 9);
  const int col = (int)(i4 & 511);
  float4 v = {0.f, 0.f, 0.f, 0.f};
  if (row < 512)      v = *(const float4*)&Wv[(size_t)row * INDIM + col];
  else if (row < 576) v = *(const float4*)&Wk[(size_t)(row - 512) * INDIM + col];
  else if (row < 640) v = *(const float4*)&Wq[(size_t)(row - 576) * INDIM + col];
  else if (row < 704) v = *(const float4*)&Wa[(size_t)(row - 640) * INDIM + col];
  ushort4 h;
  h.x = f2h(v.x); h.y = f2h(v.y); h.z = f2h(v.z); h.w = f2h(v.w);
  *(ushort4*)&wh[i4] = h;
  if (t < NPAD) {
    float b = 0.f;
    if (t < 512)      b = bv[t];
    else if (t < 576) b = bk[t - 512];
    else if (t < 640) b = bq[t - 576];
    else if (t < 704) b = ba[t - 640];
    bcat[t] = b;
  }
}

// ---------------------------------------------------------------------------
// K1: fp16 MFMA projection GEMM (M=32768,K=512,N=768), fp32 accumulate.
// Round-10: A operand read DIRECTLY from fp32 x (reg-staged: dwordx4 loads +
// v_cvt + ds_write_b128) — cast_kernel's 96 MB x-pass eliminated.  Same
// f2h rounding as before (bit-identical).  B stays gload16 from wh.
// 16-step loop macro-unrolled: counted vmcnt(6) = 4 A-loads + 2 B-gloads
// per iter; ring of 3 LDS buffers; 2 barriers/iter.  v-columns (xtile<4)
// transposed in-LDS, written as split-bf16 Bt[(cb)][d][s] (16B stores).
// ---------------------------------------------------------------------------
__global__ __launch_bounds__(256) void proj_mfma_kernel(
    const float* __restrict__ x, const unsigned short* __restrict__ wh,
    const float* __restrict__ bcat,
    unsigned short* __restrict__ Bt_h, unsigned short* __restrict__ Bt_l,
    float* __restrict__ k_ws, float* __restrict__ q_ws,
    float* __restrict__ a_ws)
{
  __shared__ __align__(16) _Float16 Ah[3][128 * 32];   // 24 KB
  __shared__ __align__(16) _Float16 Bh[3][128 * 32];   // 24 KB

  const int d     = blockIdx.x;
  const int grp   = d >> 3;                 // 0..191
  const int ytile = (d & 7) * 32 + grp / 6; // 0..255
  const int xtile = grp % 6;                // 0..5
  const int r0 = ytile * 128;
  const int c0 = xtile * 128;

  const int tid  = threadIdx.x;
  const int wave = tid >> 6, lane = tid & 63;
  const int wm   = (wave & 1) * 64, wn = (wave >> 1) * 64;
  const int fm   = lane & 15;
  const int fk   = (lane >> 4) * 8;
  const int g    = lane >> 4;

  float4_t acc[4][4];
#pragma unroll
  for (int i = 0; i < 4; ++i)
#pragma unroll
    for (int j = 0; j < 4; ++j) acc[i][j] = (float4_t)0.0f;

  const int srow = tid >> 2;           // 0..63
  const int scol = (tid & 3) * 8;      // 0,8,16,24

  const float* pX0 = x + (size_t)(r0 + srow) * INDIM + scol;
  const float* pX1 = x + (size_t)(r0 + 64 + srow) * INDIM + scol;
  const unsigned short* pB0 = wh + (size_t)(c0 + srow) * INDIM + scol;
  const unsigned short* pB1 = wh + (size_t)(c0 + 64 + srow) * INDIM + scol;

  float4 ra0[4], ra1[4];

  auto loadA = [&](float4* ra, int kt) {
    const int k0 = kt * 32;
    ra[0] = *(const float4*)(pX0 + k0);
    ra[1] = *(const float4*)(pX0 + k0 + 4);
    ra[2] = *(const float4*)(pX1 + k0);
    ra[3] = *(const float4*)(pX1 + k0 + 4);
  };
  auto writeA = [&](const float4* ra, int buf) {
    half8_t h0, h1;
    h0[0] = (_Float16)ra[0].x; h0[1] = (_Float16)ra[0].y;
    h0[2] = (_Float16)ra[0].z; h0[3] = (_Float16)ra[0].w;
    h0[4] = (_Float16)ra[1].x; h0[5] = (_Float16)ra[1].y;
    h0[6] = (_Float16)ra[1].z; h0[7] = (_Float16)ra[1].w;
    h1[0] = (_Float16)ra[2].x; h1[1] = (_Float16)ra[2].y;
    h1[2] = (_Float16)ra[2].z; h1[3] = (_Float16)ra[2].w;
    h1[4] = (_Float16)ra[3].x; h1[5] = (_Float16)ra[3].y;
    h1[6] = (_Float16)ra[3].z; h1[7] = (_Float16)ra[3].w;
    *(half8_t*)&Ah[buf][tid * 8] = h0;
    *(half8_t*)&Ah[buf][(256 + tid) * 8] = h1;
  };
  auto stageB = [&](int buf, int kt) {
    const int k0 = kt * 32;
    gload16(pB0 + k0, &Bh[buf][tid * 8]);
    gload16(pB1 + k0, &Bh[buf][(256 + tid) * 8]);
  };
  auto compute = [&](int buf) {
    half8_t a[4], b[4];
#pragma unroll
    for (int i = 0; i < 4; ++i)
      a[i] = *(const half8_t*)&Ah[buf][(wm + i * 16 + fm) * 32 + fk];
#pragma unroll
    for (int j = 0; j < 4; ++j)
      b[j] = *(const half8_t*)&Bh[buf][(wn + j * 16 + fm) * 32 + fk];
    __builtin_amdgcn_s_setprio(1);
#pragma unroll
    for (int i = 0; i < 4; ++i)
#pragma unroll
      for (int j = 0; j < 4; ++j)
        acc[i][j] = __builtin_amdgcn_mfma_f32_16x16x32_f16(a[i], b[j], acc[i][j], 0, 0, 0);
    __builtin_amdgcn_s_setprio(0);
  };

  // prologue: tiles 0,1 in flight (A regs + B LDS), 12 VMEM outstanding
  loadA(ra0, 0);
  stageB(0, 0);
  loadA(ra1, 1);
  stageB(1, 1);

  // per step T: wait A(T)/B(T) (vmcnt 6 = the 6 ops of T+1 stay in flight),
  // ds_write A(T), prefetch tile T+2, lgkm drain, barrier, MFMA, barrier.
#define PSTEP(T, RA)                                                       \
  {                                                                        \
    if ((T) < 15) asm volatile("s_waitcnt vmcnt(6)" ::: "memory");         \
    else          asm volatile("s_waitcnt vmcnt(0)" ::: "memory");         \
    writeA(RA, (T) % 3);                                                   \
    if ((T) + 2 < 16) { loadA(RA, (T) + 2); stageB(((T) + 2) % 3, (T) + 2); } \
    asm volatile("s_waitcnt lgkmcnt(0)" ::: "memory");                     \
    __builtin_amdgcn_s_barrier();                                          \
    compute((T) % 3);                                                      \
    __builtin_amdgcn_s_barrier();                                          \
  }
  PSTEP(0, ra0)  PSTEP(1, ra1)  PSTEP(2, ra0)  PSTEP(3, ra1)
  PSTEP(4, ra0)  PSTEP(5, ra1)  PSTEP(6, ra0)  PSTEP(7, ra1)
  PSTEP(8, ra0)  PSTEP(9, ra1)  PSTEP(10, ra0) PSTEP(11, ra1)
  PSTEP(12, ra0) PSTEP(13, ra1) PSTEP(14, ra0) PSTEP(15, ra1)
#undef PSTEP

  if (xtile < 4) {
    // ---- v path: LDS transpose -> Bt split-bf16 (16 B stores) ----
    unsigned int* Thl = (unsigned int*)&Ah[0][0];
    const int t0 = r0 >> 2;            // multiple of 32
    const int cb0 = (t0 >> 7) * 4;     // chunk*4
    const int s0 = t0 & 127;           // 0/32/64/96
    __syncthreads();
    for (int bb = 0; bb < 4; ++bb) {
#pragma unroll
      for (int j = 0; j < 4; ++j) {
        const int d_loc = wn + j * 16 + fm;
        const float bias = bcat[c0 + d_loc];
#pragma unroll
        for (int i = 0; i < 4; ++i) {
          const int trow = (wm >> 2) + i * 4 + g;       // 0..31
          const float val = acc[i][j][bb] + bias;
          const unsigned short h = f2bf(val);
          const unsigned short l = f2bf(val - bf2f(h));
          Thl[d_loc * 34 + trow] = (unsigned int)h | ((unsigned int)l << 16);
        }
      }
      __syncthreads();
#pragma unroll
      for (int q2 = 0; q2 < 2; ++q2) {
        const int task = q2 * 256 + tid;   // 0..511
        const int dd = task >> 2;          // 0..127
        const int tq = task & 3;           // 0..3 (8 elems each)
        const unsigned int* p = &Thl[dd * 34 + tq * 8];
        const unsigned int w0 = p[0], w1 = p[1], w2 = p[2], w3 = p[3];
        const unsigned int w4 = p[4], w5 = p[5], w6 = p[6], w7 = p[7];
        uint4 hv, lv;
        hv.x = (w0 & 0xffffu) | (w1 << 16);
        hv.y = (w2 & 0xffffu) | (w3 << 16);
        hv.z = (w4 & 0xffffu) | (w5 << 16);
        hv.w = (w6 & 0xffffu) | (w7 << 16);
        lv.x = (w0 >> 16) | (w1 & 0xffff0000u);
        lv.y = (w2 >> 16) | (w3 & 0xffff0000u);
        lv.z = (w4 >> 16) | (w5 & 0xffff0000u);
        lv.w = (w6 >> 16) | (w7 & 0xffff0000u);
        const size_t oa = ((size_t)(cb0 + bb) * DV + c0 + dd) * CHUNK + s0 + tq * 8;
        *(uint4*)&Bt_h[oa] = hv;
        *(uint4*)&Bt_l[oa] = lv;
      }
      __syncthreads();
    }
  } else {
    // ---- k/q/a path: coalesced fp32 stores ----
#pragma unroll
    for (int j = 0; j < 4; ++j) {
      const int col = c0 + wn + j * 16 + fm;
      if (col >= 704) continue;
      const float bias = bcat[col];
#pragma unroll
      for (int i = 0; i < 4; ++i) {
#pragma unroll
        for (int r = 0; r < 4; ++r) {
          const int row = r0 + wm + i * 16 + g * 4 + r;  // row = t*4+b
          const float val = acc[i][j][r] + bias;
          if (col < 576) {
            k_ws[(size_t)row * DK + col - 512] = val;
          } else if (col < 640) {
            q_ws[(size_t)row * DK + col - 576] = val;
          } else {
            a_ws[(size_t)row * DK + col - 640] = 1.0f / (1.0f + expf(-val));
          }
        }
      }
    }
  }
}

// ---------------------------------------------------------------------------
// K2: fused prep+score per (c,b).  512 threads, 96 KB LDS.
// cumprod -> q pass (Acat q-cols + LDS tile) -> k pass (LDS tile) ->
// kT transpose -> 8-wave score MFMA -> tril s-col write.
// ---------------------------------------------------------------------------
__global__ __launch_bounds__(512) void prep_kernel(
    const float* __restrict__ a_ws, const float* __restrict__ k_ws,
    const float* __restrict__ q_ws,
    unsigned short* __restrict__ Acat_h, unsigned short* __restrict__ Acat_l,
    unsigned short* __restrict__ kT_h, unsigned short* __restrict__ kT_l,
    float* __restrict__ pend)
{
  __shared__ float pal[CHUNK][DK];                        // 32 KB
  __shared__ __align__(16) unsigned short Aq_h[128 * 64]; // 16 KB
  __shared__ __align__(16) unsigned short Aq_l[128 * 64]; // 16 KB
  __shared__ __align__(16) unsigned short Bk_h[128 * 64]; // 16 KB
  __shared__ __align__(16) unsigned short Bk_l[128 * 64]; // 16 KB

  const int c = blockIdx.x, b = blockIdx.y;
  const int cb = c * B_DIM + b;
  const int tid = threadIdx.x;
  const int wave = tid >> 6, lane = tid & 63;
  const int wm = (wave & 1) * 64, wn = (wave >> 1) * 32;
  const int fm = lane & 15;
  const int fk = (lane >> 4) * 8;
  const int g  = lane >> 4;

#pragma unroll
  for (int i = 0; i < 4; ++i) {
    const int f = (i * 512 + tid) * 4;       // 0..8191
    const int t = f >> 6, n0 = f & 63;
    const float4 av = *(const float4*)&a_ws[(size_t)(c * CHUNK + t) * 256 + b * 64 + n0];
    *(float4*)&pal[t][n0] = av;
  }
  __syncthreads();

  if (tid < 64) {
    float p = 1.0f;
#pragma unroll 4
    for (int t = 0; t < CHUNK; ++t) {
      p *= fmaxf(pal[t][tid], EPSF);
      pal[t][tid] = p;
    }
    pend[c * 256 + b * 64 + tid] = p;
  }
  __syncthreads();

#pragma unroll
  for (int i = 0; i < 4; ++i) {
    const int f = (i * 512 + tid) * 4;
    const int t = f >> 6, n0 = f & 63;
    const float4 qv = *(const float4*)&q_ws[(size_t)(c * CHUNK + t) * 256 + b * 64 + n0];
    const size_t qa = ((size_t)cb * CHUNK + t) * KCAT + 128 + n0;
    float q0 = qv.x * pal[t][n0 + 0];
    float q1 = qv.y * pal[t][n0 + 1];
    float q2 = qv.z * pal[t][n0 + 2];
    float q3 = qv.w * pal[t][n0 + 3];
    ushort4 h, l;
    h.x = f2bf(q0); l.x = f2bf(q0 - bf2f(h.x));
    h.y = f2bf(q1); l.y = f2bf(q1 - bf2f(h.y));
    h.z = f2bf(q2); l.z = f2bf(q2 - bf2f(h.z));
    h.w = f2bf(q3); l.w = f2bf(q3 - bf2f(h.w));
    *(ushort4*)&Acat_h[qa] = h;
    *(ushort4*)&Acat_l[qa] = l;
    const int wi = t * 64 + (n0 ^ ((t & 7) << 3));
    *(ushort4*)&Aq_h[wi] = h;
    *(ushort4*)&Aq_l[wi] = l;
  }

#pragma unroll
  for (int i = 0; i < 4; ++i) {
    const int f = (i * 512 + tid) * 4;
    const int t = f >> 6, n0 = f & 63;
    const float4 kv = *(const float4*)&k_ws[(size_t)(c * CHUNK + t) * 256 + b * 64 + n0];
    float k0 = kv.x / (pal[t][n0 + 0] + EPSF);
    float k1 = kv.y / (pal[t][n0 + 1] + EPSF);
    float k2 = kv.z / (pal[t][n0 + 2] + EPSF);
    float k3 = kv.w / (pal[t][n0 + 3] + EPSF);
    ushort4 h, l;
    h.x = f2bf(k0); l.x = f2bf(k0 - bf2f(h.x));
    h.y = f2bf(k1); l.y = f2bf(k1 - bf2f(h.y));
    h.z = f2bf(k2); l.z = f2bf(k2 - bf2f(h.z));
    h.w = f2bf(k3); l.w = f2bf(k3 - bf2f(h.w));
    const int wi = t * 64 + (n0 ^ ((t & 7) << 3));
    *(ushort4*)&Bk_h[wi] = h;
    *(ushort4*)&Bk_l[wi] = l;
  }
  __syncthreads();

#pragma unroll
  for (int it = 0; it < 2; ++it) {
    const int task = it * 512 + tid;    // 0..1023
    const int n  = task >> 4;           // 0..63
    const int tg = task & 15;           // 0..15
    ushort4 h0, h1, l0, l1;
    unsigned short hh[8], ll[8];
#pragma unroll
    for (int e = 0; e < 8; ++e) {
      const int wi = (tg * 8 + e) * 64 + (n ^ (e << 3));
      hh[e] = Bk_h[wi];
      ll[e] = Bk_l[wi];
    }
    h0.x = hh[0]; h0.y = hh[1]; h0.z = hh[2]; h0.w = hh[3];
    h1.x = hh[4]; h1.y = hh[5]; h1.z = hh[6]; h1.w = hh[7];
    l0.x = ll[0]; l0.y = ll[1]; l0.z = ll[2]; l0.w = ll[3];
    l1.x = ll[4]; l1.y = ll[5]; l1.z = ll[6]; l1.w = ll[7];
    const size_t oa = ((size_t)cb * DK + n) * CHUNK + tg * 8;
    *(ushort4*)&kT_h[oa]     = h0;
    *(ushort4*)&kT_h[oa + 4] = h1;
    *(ushort4*)&kT_l[oa]     = l0;
    *(ushort4*)&kT_l[oa + 4] = l1;
  }

  float4_t acc[4][2];
#pragma unroll
  for (int i = 0; i < 4; ++i)
#pragma unroll
    for (int j = 0; j < 2; ++j) acc[i][j] = (float4_t)0.0f;

#pragma unroll
  for (int ksub = 0; ksub < 2; ++ksub) {
    short8_t a_hi[4], a_lo[4], b_hi[2], b_lo[2];
#pragma unroll
    for (int i = 0; i < 4; ++i) {
      const int r = wm + i * 16 + fm;
      const int ar = r * 64 + ((ksub * 32 + fk) ^ ((r & 7) << 3));
      a_hi[i] = *(const short8_t*)&Aq_h[ar];
      a_lo[i] = *(const short8_t*)&Aq_l[ar];
    }
#pragma unroll
    for (int j = 0; j < 2; ++j) {
      const int r = wn + j * 16 + fm;
      const int br = r * 64 + ((ksub * 32 + fk) ^ ((r & 7) << 3));
      b_hi[j] = *(const short8_t*)&Bk_h[br];
      b_lo[j] = *(const short8_t*)&Bk_l[br];
    }
    __builtin_amdgcn_s_setprio(1);
#pragma unroll
    for (int i = 0; i < 4; ++i)
#pragma unroll
      for (int j = 0; j < 2; ++j) {
        acc[i][j] = __builtin_amdgcn_mfma_f32_16x16x32_bf16(a_hi[i], b_hi[j], acc[i][j], 0, 0, 0);
        acc[i][j] = __builtin_amdgcn_mfma_f32_16x16x32_bf16(a_lo[i], b_hi[j], acc[i][j], 0, 0, 0);
        acc[i][j] = __builtin_amdgcn_mfma_f32_16x16x32_bf16(a_hi[i], b_lo[j], acc[i][j], 0, 0, 0);
      }
    __builtin_amdgcn_s_setprio(0);
  }

#pragma unroll
  for (int j = 0; j < 2; ++j) {
    const int s = wn + j * 16 + fm;
#pragma unroll
    for (int i = 0; i < 4; ++i) {
#pragma unroll
      for (int r = 0; r < 4; ++r) {
        const int t = wm + i * 16 + g * 4 + r;
        const float vv = (s <= t) ? acc[i][j][r] : 0.0f;
        const unsigned short h = f2bf(vv);
        const size_t oa = ((size_t)cb * CHUNK + t) * KCAT + s;
        Acat_h[oa] = h;
        Acat_l[oa] = f2bf(vv - bf2f(h));
      }
    }
  }
}

// ---------------------------------------------------------------------------
// K3: wchunk via MFMA.  W[d][n] = (sum_t v^T[d][t]*k_t[t][n]) * pend[n].
// B-operand from kT (split-bf16, slot-swizzled gload16).  XCD-grouped grid.
// ---------------------------------------------------------------------------
__global__ __launch_bounds__(256) void wchunk_mfma_kernel(
    const unsigned short* __restrict__ Bt_h, const unsigned short* __restrict__ Bt_l,
    const unsigned short* __restrict__ kT_h, const unsigned short* __restrict__ kT_l,
    const float* __restrict__ pend, float* __restrict__ W_ws)
{
  __shared__ __align__(16) unsigned short Ah[128 * 32];  //  8 KB
  __shared__ __align__(16) unsigned short Al[128 * 32];  //  8 KB
  __shared__ __align__(16) unsigned short Kh[64 * 128];  // 16 KB
  __shared__ __align__(16) unsigned short Kl[64 * 128];  // 16 KB

  const int bd = blockIdx.x;
  const int cb = (bd >> 5) * 8 + (bd & 7);
  const int dt = (bd >> 3) & 3;
  const int tid  = threadIdx.x;
  const int wave = tid >> 6, lane = tid & 63;
  const int wm   = (wave & 1) * 64;
  const int wn   = (wave >> 1) * 32;
  const int fm   = lane & 15;
  const int fk   = (lane >> 4) * 8;

  const unsigned short* Ab_h = Bt_h + ((size_t)cb * DV + dt * 128) * CHUNK;
  const unsigned short* Ab_l = Bt_l + ((size_t)cb * DV + dt * 128) * CHUNK;
  const unsigned short* Kb_h = kT_h + (size_t)cb * DK * CHUNK;
  const unsigned short* Kb_l = kT_l + (size_t)cb * DK * CHUNK;

#pragma unroll
  for (int it = 0; it < 4; ++it) {
    const int tk = it * 256 + tid;      // 0..1023
    const int n = tk >> 4, slot = tk & 15;
    gload16(&Kb_h[(size_t)n * CHUNK + ((slot ^ (n & 15)) << 3)], &Kh[tk * 8]);
    gload16(&Kb_l[(size_t)n * CHUNK + ((slot ^ (n & 15)) << 3)], &Kl[tk * 8]);
  }

  float4_t acc[4][2];
#pragma unroll
  for (int i = 0; i < 4; ++i)
#pragma unroll
    for (int j = 0; j < 2; ++j) acc[i][j] = (float4_t)0.0f;

  for (int ks = 0; ks < 4; ++ks) {
    const int k0 = ks * 32;
#pragma unroll
    for (int q = 0; q < 2; ++q) {
      const int flat = (q * 256 + tid) * 8;
      const int row = flat >> 5, col = flat & 31;
      gload16(&Ab_h[(size_t)row * CHUNK + k0 + col], &Ah[flat]);
      gload16(&Ab_l[(size_t)row * CHUNK + k0 + col], &Al[flat]);
    }
    __syncthreads();

    short8_t a_hi[4], a_lo[4], b_hi[2], b_lo[2];
#pragma unroll
    for (int i = 0; i < 4; ++i) {
      const int ar = (wm + i * 16 + fm) * 32 + fk;
      a_hi[i] = *(const short8_t*)&Ah[ar];
      a_lo[i] = *(const short8_t*)&Al[ar];
    }
#pragma unroll
    for (int j = 0; j < 2; ++j) {
      const int n = wn + j * 16 + fm;
      const int slot = (k0 + fk) >> 3;
      const int addr = n * CHUNK + ((slot ^ (n & 15)) << 3);
      b_hi[j] = *(const short8_t*)&Kh[addr];
      b_lo[j] = *(const short8_t*)&Kl[addr];
    }
#pragma unroll
    for (int i = 0; i < 4; ++i)
#pragma unroll
      for (int j = 0; j < 2; ++j) {
        acc[i][j] = __builtin_amdgcn_mfma_f32_16x16x32_bf16(a_hi[i], b_hi[j], acc[i][j], 0, 0, 0);
        acc[i][j] = __builtin_amdgcn_mfma_f32_16x16x32_bf16(a_lo[i], b_hi[j], acc[i][j], 0, 0, 0);
        acc[i][j] = __builtin_amdgcn_mfma_f32_16x16x32_bf16(a_hi[i], b_lo[j], acc[i][j], 0, 0, 0);
      }
    __syncthreads();
  }

#pragma unroll
  for (int j = 0; j < 2; ++j) {
    const int n = wn + j * 16 + fm;
    const float pj = pend[(cb >> 2) * 256 + (cb & 3) * 64 + n];
#pragma unroll
    for (int i = 0; i < 4; ++i) {
#pragma unroll
      for (int r = 0; r < 4; ++r) {
        const int dd = dt * 128 + wm + i * 16 + (lane >> 4) * 4 + r;
        W_ws[((size_t)cb * DV + dd) * DK + n] = acc[i][j][r] * pj;
      }
    }
  }
}

// ---------------------------------------------------------------------------
// K4: sequential state scan over chunks.  Emits pre-update state S_c as
// split-bf16 (Sh/Sl) for out_mfma's uniform global_load_lds staging.
// ---------------------------------------------------------------------------
__global__ __launch_bounds__(256) void scan_kernel(
    const float* __restrict__ W_ws, const float* __restrict__ pend,
    unsigned short* __restrict__ Sh, unsigned short* __restrict__ Sl)
{
  const int flat = blockIdx.x * 256 + threadIdx.x;
  const int n = flat & 63;
  const int bd = flat >> 6;
  const int b = bd >> 9;
  float s = 0.0f;
  for (int c = 0; c < NCH; ++c) {
    const int off = c * 131072 + flat;
    const float w = W_ws[off];
    const unsigned short h = f2bf(s);
    Sh[off] = h;
    Sl[off] = f2bf(s - bf2f(h));
    s = s * pend[c * 256 + b * 64 + n] + w;
  }
}

// ---------------------------------------------------------------------------
// K6: y = [A|q_t] @ [v ; S^T].  3 uniform K=64 XOR-swizzled steps.
// XCD-grouped 1D grid (4 nt-blocks of one (c,b) share an XCD's L2).
// ---------------------------------------------------------------------------
__global__ __launch_bounds__(256) void out_mfma_kernel(
    const unsigned short* __restrict__ Acat_h, const unsigned short* __restrict__ Acat_l,
    const unsigned short* __restrict__ Bt_h, const unsigned short* __restrict__ Bt_l,
    const unsigned short* __restrict__ Sh, const unsigned short* __restrict__ Sl,
    float* __restrict__ out)
{
  __shared__ __align__(16) unsigned short Ah[128 * 64];
  __shared__ __align__(16) unsigned short Al[128 * 64];
  __shared__ __align__(16) unsigned short Bh[128 * 64];
  __shared__ __align__(16) unsigned short Bl[128 * 64];

  const int bd = blockIdx.x;
  const int cb = (bd >> 5) * 8 + (bd & 7);
  const int nt = (bd >> 3) & 3;
  const int c = cb >> 2, b = cb & 3;
  const int tid  = threadIdx.x;
  const int wave = tid >> 6, lane = tid & 63;
  const int wm   = (wave & 1) * 64, wn = (wave >> 1) * 64;
  const int fm   = lane & 15;
  const int fk   = (lane >> 4) * 8;

  const unsigned short* Ab_h = Acat_h + (size_t)cb * CHUNK * KCAT;
  const unsigned short* Ab_l = Acat_l + (size_t)cb * CHUNK * KCAT;
  const unsigned short* Bb_h = Bt_h + ((size_t)cb * DV + nt * 128) * CHUNK;
  const unsigned short* Bb_l = Bt_l + ((size_t)cb * DV + nt * 128) * CHUNK;
  const unsigned short* Sb_h = Sh + ((size_t)cb * DV + nt * 128) * DK;
  const unsigned short* Sb_l = Sl + ((size_t)cb * DV + nt * 128) * DK;

  const int srow = tid >> 3;          // 0..31
  const int scolB = (tid & 7) * 16;
  const int sc = (scolB ^ ((srow & 7) << 4)) >> 1;   // halfs
  const int sdst = srow * 64 + (scolB >> 1);

  float4_t acc[4][4];
#pragma unroll
  for (int i = 0; i < 4; ++i)
#pragma unroll
    for (int j = 0; j < 4; ++j) acc[i][j] = (float4_t)0.0f;

  for (int ks = 0; ks < 3; ++ks) {
    const int k0 = ks * 64;
#pragma unroll
    for (int q = 0; q < 4; ++q) {
      const int row = q * 32 + srow;
      const int dst = q * 2048 + sdst;
      gload16(&Ab_h[(size_t)row * KCAT + k0 + sc], &Ah[dst]);
      gload16(&Ab_l[(size_t)row * KCAT + k0 + sc], &Al[dst]);
      if (ks < 2) {
        gload16(&Bb_h[(size_t)row * CHUNK + k0 + sc], &Bh[dst]);
        gload16(&Bb_l[(size_t)row * CHUNK + k0 + sc], &Bl[dst]);
      } else {
        gload16(&Sb_h[(size_t)row * DK + sc], &Bh[dst]);
        gload16(&Sb_l[(size_t)row * DK + sc], &Bl[dst]);
      }
    }
    __syncthreads();

#pragma unroll
    for (int ksub = 0; ksub < 2; ++ksub) {
      short8_t a_hi[4], a_lo[4], b_hi[4], b_lo[4];
#pragma unroll
      for (int i = 0; i < 4; ++i) {
        const int r = wm + i * 16 + fm;
        const int ar = r * 64 + ((ksub * 32 + fk) ^ ((r & 7) << 3));
        a_hi[i] = *(const short8_t*)&Ah[ar];
        a_lo[i] = *(const short8_t*)&Al[ar];
      }
#pragma unroll
      for (int j = 0; j < 4; ++j) {
        const int r = wn + j * 16 + fm;
        const int br = r * 64 + ((ksub * 32 + fk) ^ ((r & 7) << 3));
        b_hi[j] = *(const short8_t*)&Bh[br];
        b_lo[j] = *(const short8_t*)&Bl[br];
      }
      __builtin_amdgcn_s_setprio(1);
#pragma unroll
      for (int i = 0; i < 4; ++i)
#pragma unroll
        for (int j = 0; j < 4; ++j) {
          acc[i][j] = __builtin_amdgcn_mfma_f32_16x16x32_bf16(a_hi[i], b_hi[j], acc[i][j], 0, 0, 0);
          acc[i][j] = __builtin_amdgcn_mfma_f32_16x16x32_bf16(a_lo[i], b_hi[j], acc[i][j], 0, 0, 0);
          acc[i][j] = __builtin_amdgcn_mfma_f32_16x16x32_bf16(a_hi[i], b_lo[j], acc[i][j], 0, 0, 0);
        }
      __builtin_amdgcn_s_setprio(0);
    }
    __syncthreads();
  }

#pragma unroll
  for (int j = 0; j < 4; ++j) {
    const int d = nt * 128 + wn + j * 16 + fm;
#pragma unroll
    for (int i = 0; i < 4; ++i) {
#pragma unroll
      for (int r = 0; r < 4; ++r) {
        const int t = c * CHUNK + wm + i * 16 + (lane >> 4) * 4 + r;
        out[((size_t)t * B_DIM + b) * DV + d] = acc[i][j][r];
      }
    }
  }
}

// ---------------------------------------------------------------------------
extern "C" void kernel_launch(void* const* d_in, const int* in_sizes, int n_in,
                              void* d_out, int out_size, void* d_ws, size_t ws_size,
                              hipStream_t stream)
{
  const float* x  = (const float*)d_in[0];
  const float* Wv = (const float*)d_in[1];
  const float* bv = (const float*)d_in[2];
  const float* Wk = (const float*)d_in[3];
  const float* bk = (const float*)d_in[4];
  const float* Wq = (const float*)d_in[5];
  const float* bq = (const float*)d_in[6];
  const float* Wa = (const float*)d_in[7];
  const float* ba = (const float*)d_in[8];
  float* out = (float*)d_out;

  // ---- workspace layout ----
  float* ws   = (float*)d_ws;
  // Bt occupies the first 64 MB, written directly by proj.
  unsigned short* Bt_h = (unsigned short*)ws;               // 16,777,216 us
  unsigned short* Bt_l = Bt_h + (size_t)NCH * B_DIM * DV * CHUNK;
  float* k_ws = ws + (size_t)ROWS * DV;                     //  2,097,152 f (raw k)
  float* a_ws = k_ws + (size_t)ROWS * DK;                   //  2,097,152 f
  float* pend = a_ws + (size_t)ROWS * DK;                   //     16,384 f
  float* W_ws = pend + NCH * B_DIM * DK;                    //  8,388,608 f
  float* bcat = W_ws + (size_t)NCH * B_DIM * DV * DK;       //        768 f
  unsigned short* Acat_h = (unsigned short*)(bcat + NPAD);  //  6,291,456 us
  unsigned short* Acat_l = Acat_h + (size_t)NCH * B_DIM * CHUNK * KCAT;
  unsigned short* uni = Acat_l + (size_t)NCH * B_DIM * CHUNK * KCAT;
  // uni byte map: [0,32M) Sh/Sl (scan->out); [32M,32.75M) wh (wcast->proj);
  // [36M,44M) q_ws fp32 (proj->prep); [44M,60M) kT (prep->wchunk).
  unsigned short* S_h = uni;                                //  8,388,608 us
  unsigned short* S_l = S_h + (size_t)NCH * B_DIM * DV * DK;
  unsigned short* wh = uni + (size_t)ROWS * INDIM;          //    393,216 us
  float* q_ws = (float*)(uni + (size_t)18 * 1024 * 1024);   //  2,097,152 f
  unsigned short* kT_h = (unsigned short*)(q_ws + (size_t)ROWS * DK);
  unsigned short* kT_l = kT_h + (size_t)NCH * B_DIM * DK * CHUNK;

  wcast_kernel<<<384, 256, 0, stream>>>(
      Wv, Wk, Wq, Wa, bv, bk, bq, ba, wh, bcat);
  proj_mfma_kernel<<<(ROWS / 128) * (NPAD / 128), 256, 0, stream>>>(
      x, wh, bcat, Bt_h, Bt_l, k_ws, q_ws, a_ws);
  prep_kernel<<<dim3(NCH, B_DIM), 512, 0, stream>>>(
      a_ws, k_ws, q_ws, Acat_h, Acat_l, kT_h, kT_l, pend);
  wchunk_mfma_kernel<<<NCH * B_DIM * 4, 256, 0, stream>>>(
      Bt_h, Bt_l, kT_h, kT_l, pend, W_ws);
  scan_kernel<<<(B_DIM * DV * DK) / 256, 256, 0, stream>>>(
      W_ws, pend, S_h, S_l);
  out_mfma_kernel<<<NCH * B_DIM * 4, 256, 0, stream>>>(
      Acat_h, Acat_l, Bt_h, Bt_l, S_h, S_l, out);
}

// Round 7
// 266.568 us; speedup vs baseline: 1.0664x; 1.0664x over previous
//
#include <hip/hip_runtime.h>
#include <math.h>

#define T_DIM 8192
#define B_DIM 4
#define INDIM 512
#define DV 512
#define DK 64
#define CHUNK 128
#define NCH (T_DIM / CHUNK)     // 64
#define ROWS (T_DIM * B_DIM)    // 32768
#define NPAD 768                // 704 proj cols padded to 6x128
#define KCAT 192                // 128 intra + 64 state
#define EPSF 1e-8f

typedef float float4_t __attribute__((ext_vector_type(4)));
typedef short short8_t __attribute__((ext_vector_type(8)));
typedef _Float16 half8_t __attribute__((ext_vector_type(8)));

__device__ inline unsigned short f2bf(float f) {
  unsigned int u = __float_as_uint(f);
  unsigned int r = (u + 0x7fffu + ((u >> 16) & 1u)) >> 16;
  return (unsigned short)r;
}
__device__ inline float bf2f(unsigned short h) {
  return __uint_as_float(((unsigned int)h) << 16);
}
__device__ inline unsigned short f2h(float f) {
  _Float16 h = (_Float16)f;
  unsigned short u;
  __builtin_memcpy(&u, &h, 2);
  return u;
}

__device__ inline void gload16(const void* g, void* l) {
  __builtin_amdgcn_global_load_lds(
      (const __attribute__((address_space(1))) void*)g,
      (__attribute__((address_space(3))) void*)l, 16, 0, 0);
}

// ---------------------------------------------------------------------------
// C0: merged fp16 cast.  blocks [0,16384): x -> xh (fp16).
// blocks [16384,16768): padded concat weights -> wh (fp16) + bcat.
// (Round-7 lesson: proj MUST consume fp16 via global_load_lds — direct fp32
// reg-staging doubled proj's time.  This kernel stays.)
// ---------------------------------------------------------------------------
__global__ __launch_bounds__(256) void cast_kernel(
    const float* __restrict__ x,
    const float* __restrict__ Wv, const float* __restrict__ Wk,
    const float* __restrict__ Wq, const float* __restrict__ Wa,
    const float* __restrict__ bv, const float* __restrict__ bk,
    const float* __restrict__ bq, const float* __restrict__ ba,
    unsigned short* __restrict__ xh, unsigned short* __restrict__ wh,
    float* __restrict__ bcat)
{
  if (blockIdx.x < 16384) {
    const size_t i4 = ((size_t)blockIdx.x * 256 + threadIdx.x) * 4;
    const float4 v = *(const float4*)&x[i4];
    ushort4 h;
    h.x = f2h(v.x); h.y = f2h(v.y); h.z = f2h(v.z); h.w = f2h(v.w);
    *(ushort4*)&xh[i4] = h;
  } else {
    const int t = (blockIdx.x - 16384) * 256 + threadIdx.x;
    const size_t i4 = (size_t)t * 4;
    const int row = (int)(i4 >> 9);
    const int col = (int)(i4 & 511);
    float4 v = {0.f, 0.f, 0.f, 0.f};
    if (row < 512)      v = *(const float4*)&Wv[(size_t)row * INDIM + col];
    else if (row < 576) v = *(const float4*)&Wk[(size_t)(row - 512) * INDIM + col];
    else if (row < 640) v = *(const float4*)&Wq[(size_t)(row - 576) * INDIM + col];
    else if (row < 704) v = *(const float4*)&Wa[(size_t)(row - 640) * INDIM + col];
    ushort4 h;
    h.x = f2h(v.x); h.y = f2h(v.y); h.z = f2h(v.z); h.w = f2h(v.w);
    *(ushort4*)&wh[i4] = h;
    if (t < NPAD) {
      float b = 0.f;
      if (t < 512)      b = bv[t];
      else if (t < 576) b = bk[t - 512];
      else if (t < 640) b = bq[t - 576];
      else if (t < 704) b = ba[t - 640];
      bcat[t] = b;
    }
  }
}

// ---------------------------------------------------------------------------
// K1: fp16 MFMA projection GEMM (M=32768,K=512,N=768), fp32 accumulate.
// v-columns (xtile<4) transposed in-LDS, written directly as split-bf16
// Bt[(cb)][d][s].  3-buffer ring, depth-2 prefetch via global_load_lds
// (async DMA — do NOT reg-stage), XCD-grouped mapping.  [round-5 proven]
// ---------------------------------------------------------------------------
__global__ __launch_bounds__(256) void proj_mfma_kernel(
    const unsigned short* __restrict__ xh, const unsigned short* __restrict__ wh,
    const float* __restrict__ bcat,
    unsigned short* __restrict__ Bt_h, unsigned short* __restrict__ Bt_l,
    float* __restrict__ k_ws, float* __restrict__ q_ws,
    float* __restrict__ a_ws)
{
  __shared__ __align__(16) _Float16 Ah[3][128 * 32];   // 24 KB
  __shared__ __align__(16) _Float16 Bh[3][128 * 32];   // 24 KB

  const int d     = blockIdx.x;
  const int grp   = d >> 3;                 // 0..191
  const int ytile = (d & 7) * 32 + grp / 6; // 0..255
  const int xtile = grp % 6;                // 0..5
  const int r0 = ytile * 128;
  const int c0 = xtile * 128;

  const int tid  = threadIdx.x;
  const int wave = tid >> 6, lane = tid & 63;
  const int wm   = (wave & 1) * 64, wn = (wave >> 1) * 64;
  const int fm   = lane & 15;
  const int fk   = (lane >> 4) * 8;
  const int g    = lane >> 4;

  float4_t acc[4][4];
#pragma unroll
  for (int i = 0; i < 4; ++i)
#pragma unroll
    for (int j = 0; j < 4; ++j) acc[i][j] = (float4_t)0.0f;

  const int srow = tid >> 2;           // 0..63
  const int scol = (tid & 3) * 8;      // 0,8,16,24

  const unsigned short* pA0 = xh + (size_t)(r0 + srow) * INDIM + scol;
  const unsigned short* pA1 = xh + (size_t)(r0 + 64 + srow) * INDIM + scol;
  const unsigned short* pB0 = wh + (size_t)(c0 + srow) * INDIM + scol;
  const unsigned short* pB1 = wh + (size_t)(c0 + 64 + srow) * INDIM + scol;

  auto stage = [&](int buf, int k0) {
    gload16(pA0 + k0, &Ah[buf][tid * 8]);
    gload16(pA1 + k0, &Ah[buf][(256 + tid) * 8]);
    gload16(pB0 + k0, &Bh[buf][tid * 8]);
    gload16(pB1 + k0, &Bh[buf][(256 + tid) * 8]);
  };

  auto compute = [&](int buf) {
    half8_t a[4], b[4];
#pragma unroll
    for (int i = 0; i < 4; ++i)
      a[i] = *(const half8_t*)&Ah[buf][(wm + i * 16 + fm) * 32 + fk];
#pragma unroll
    for (int j = 0; j < 4; ++j)
      b[j] = *(const half8_t*)&Bh[buf][(wn + j * 16 + fm) * 32 + fk];
    __builtin_amdgcn_s_setprio(1);
#pragma unroll
    for (int i = 0; i < 4; ++i)
#pragma unroll
      for (int j = 0; j < 4; ++j)
        acc[i][j] = __builtin_amdgcn_mfma_f32_16x16x32_f16(a[i], b[j], acc[i][j], 0, 0, 0);
    __builtin_amdgcn_s_setprio(0);
  };

  stage(0, 0);
  stage(1, 32);
  int cur = 0;
  for (int t = 0; t < 14; ++t) {
    stage((cur + 2) % 3, (t + 2) * 32);
    asm volatile("s_waitcnt vmcnt(8)" ::: "memory");
    __builtin_amdgcn_s_barrier();
    compute(cur);
    __builtin_amdgcn_s_barrier();
    cur = (cur + 1) % 3;
  }
  asm volatile("s_waitcnt vmcnt(4)" ::: "memory");
  __builtin_amdgcn_s_barrier();
  compute(cur);
  cur = (cur + 1) % 3;
  asm volatile("s_waitcnt vmcnt(0)" ::: "memory");
  __builtin_amdgcn_s_barrier();
  compute(cur);

  if (xtile < 4) {
    // ---- v path: LDS transpose -> Bt split-bf16 ----
    unsigned int* Thl = (unsigned int*)&Ah[0][0];
    const int t0 = r0 >> 2;            // multiple of 32
    const int cb0 = (t0 >> 7) * 4;     // chunk*4
    const int s0 = t0 & 127;           // 0/32/64/96
    __syncthreads();
    for (int bb = 0; bb < 4; ++bb) {
#pragma unroll
      for (int j = 0; j < 4; ++j) {
        const int d_loc = wn + j * 16 + fm;
        const float bias = bcat[c0 + d_loc];
#pragma unroll
        for (int i = 0; i < 4; ++i) {
          const int trow = (wm >> 2) + i * 4 + g;       // 0..31
          const float val = acc[i][j][bb] + bias;
          const unsigned short h = f2bf(val);
          const unsigned short l = f2bf(val - bf2f(h));
          Thl[d_loc * 34 + trow] = (unsigned int)h | ((unsigned int)l << 16);
        }
      }
      __syncthreads();
#pragma unroll
      for (int q2 = 0; q2 < 4; ++q2) {
        const int task = q2 * 256 + tid;   // 0..1023
        const int dd = task >> 3;          // 0..127
        const int tq = task & 7;           // 0..7
        const unsigned int* p = &Thl[dd * 34 + tq * 4];
        const unsigned int w0 = p[0], w1 = p[1], w2 = p[2], w3 = p[3];
        ushort4 hh, ll;
        hh.x = (unsigned short)w0; ll.x = (unsigned short)(w0 >> 16);
        hh.y = (unsigned short)w1; ll.y = (unsigned short)(w1 >> 16);
        hh.z = (unsigned short)w2; ll.z = (unsigned short)(w2 >> 16);
        hh.w = (unsigned short)w3; ll.w = (unsigned short)(w3 >> 16);
        const size_t oa = ((size_t)(cb0 + bb) * DV + c0 + dd) * CHUNK + s0 + tq * 4;
        *(ushort4*)&Bt_h[oa] = hh;
        *(ushort4*)&Bt_l[oa] = ll;
      }
      __syncthreads();
    }
  } else {
    // ---- k/q/a path: coalesced fp32 stores ----
#pragma unroll
    for (int j = 0; j < 4; ++j) {
      const int col = c0 + wn + j * 16 + fm;
      if (col >= 704) continue;
      const float bias = bcat[col];
#pragma unroll
      for (int i = 0; i < 4; ++i) {
#pragma unroll
        for (int r = 0; r < 4; ++r) {
          const int row = r0 + wm + i * 16 + g * 4 + r;  // row = t*4+b
          const float val = acc[i][j][r] + bias;
          if (col < 576) {
            k_ws[(size_t)row * DK + col - 512] = val;
          } else if (col < 640) {
            q_ws[(size_t)row * DK + col - 576] = val;
          } else {
            a_ws[(size_t)row * DK + col - 640] = 1.0f / (1.0f + expf(-val));
          }
        }
      }
    }
  }
}

// ---------------------------------------------------------------------------
// K2: fused prep+score per (c,b).  512 threads, 96 KB LDS.
// Round-7: 1D XCD-grouped grid — the 4 b-siblings of one chunk c run
// consecutively on one XCD, so their shared 128 KB a/q/k spans L2-hit.
// cumprod -> q pass -> k pass -> kT transpose -> 8-wave score MFMA.
// ---------------------------------------------------------------------------
__global__ __launch_bounds__(512) void prep_kernel(
    const float* __restrict__ a_ws, const float* __restrict__ k_ws,
    const float* __restrict__ q_ws,
    unsigned short* __restrict__ Acat_h, unsigned short* __restrict__ Acat_l,
    unsigned short* __restrict__ kT_h, unsigned short* __restrict__ kT_l,
    float* __restrict__ pend)
{
  __shared__ float pal[CHUNK][DK];                        // 32 KB
  __shared__ __align__(16) unsigned short Aq_h[128 * 64]; // 16 KB
  __shared__ __align__(16) unsigned short Aq_l[128 * 64]; // 16 KB
  __shared__ __align__(16) unsigned short Bk_h[128 * 64]; // 16 KB
  __shared__ __align__(16) unsigned short Bk_l[128 * 64]; // 16 KB

  const int bd = blockIdx.x;                 // 0..255
  const int l  = (bd & 7) * 32 + (bd >> 3);  // XCD-grouped logical id
  const int c = l >> 2, b = l & 3;
  const int cb = c * B_DIM + b;
  const int tid = threadIdx.x;
  const int wave = tid >> 6, lane = tid & 63;
  const int wm = (wave & 1) * 64, wn = (wave >> 1) * 32;
  const int fm = lane & 15;
  const int fk = (lane >> 4) * 8;
  const int g  = lane >> 4;

#pragma unroll
  for (int i = 0; i < 4; ++i) {
    const int f = (i * 512 + tid) * 4;       // 0..8191
    const int t = f >> 6, n0 = f & 63;
    const float4 av = *(const float4*)&a_ws[(size_t)(c * CHUNK + t) * 256 + b * 64 + n0];
    *(float4*)&pal[t][n0] = av;
  }
  __syncthreads();

  if (tid < 64) {
    float p = 1.0f;
#pragma unroll 4
    for (int t = 0; t < CHUNK; ++t) {
      p *= fmaxf(pal[t][tid], EPSF);
      pal[t][tid] = p;
    }
    pend[c * 256 + b * 64 + tid] = p;
  }
  __syncthreads();

#pragma unroll
  for (int i = 0; i < 4; ++i) {
    const int f = (i * 512 + tid) * 4;
    const int t = f >> 6, n0 = f & 63;
    const float4 qv = *(const float4*)&q_ws[(size_t)(c * CHUNK + t) * 256 + b * 64 + n0];
    const size_t qa = ((size_t)cb * CHUNK + t) * KCAT + 128 + n0;
    float q0 = qv.x * pal[t][n0 + 0];
    float q1 = qv.y * pal[t][n0 + 1];
    float q2 = qv.z * pal[t][n0 + 2];
    float q3 = qv.w * pal[t][n0 + 3];
    ushort4 h, l4;
    h.x = f2bf(q0); l4.x = f2bf(q0 - bf2f(h.x));
    h.y = f2bf(q1); l4.y = f2bf(q1 - bf2f(h.y));
    h.z = f2bf(q2); l4.z = f2bf(q2 - bf2f(h.z));
    h.w = f2bf(q3); l4.w = f2bf(q3 - bf2f(h.w));
    *(ushort4*)&Acat_h[qa] = h;
    *(ushort4*)&Acat_l[qa] = l4;
    const int wi = t * 64 + (n0 ^ ((t & 7) << 3));
    *(ushort4*)&Aq_h[wi] = h;
    *(ushort4*)&Aq_l[wi] = l4;
  }

#pragma unroll
  for (int i = 0; i < 4; ++i) {
    const int f = (i * 512 + tid) * 4;
    const int t = f >> 6, n0 = f & 63;
    const float4 kv = *(const float4*)&k_ws[(size_t)(c * CHUNK + t) * 256 + b * 64 + n0];
    float k0 = kv.x / (pal[t][n0 + 0] + EPSF);
    float k1 = kv.y / (pal[t][n0 + 1] + EPSF);
    float k2 = kv.z / (pal[t][n0 + 2] + EPSF);
    float k3 = kv.w / (pal[t][n0 + 3] + EPSF);
    ushort4 h, l4;
    h.x = f2bf(k0); l4.x = f2bf(k0 - bf2f(h.x));
    h.y = f2bf(k1); l4.y = f2bf(k1 - bf2f(h.y));
    h.z = f2bf(k2); l4.z = f2bf(k2 - bf2f(h.z));
    h.w = f2bf(k3); l4.w = f2bf(k3 - bf2f(h.w));
    const int wi = t * 64 + (n0 ^ ((t & 7) << 3));
    *(ushort4*)&Bk_h[wi] = h;
    *(ushort4*)&Bk_l[wi] = l4;
  }
  __syncthreads();

#pragma unroll
  for (int it = 0; it < 2; ++it) {
    const int task = it * 512 + tid;    // 0..1023
    const int n  = task >> 4;           // 0..63
    const int tg = task & 15;           // 0..15
    ushort4 h0, h1, l0, l1;
    unsigned short hh[8], ll[8];
#pragma unroll
    for (int e = 0; e < 8; ++e) {
      const int wi = (tg * 8 + e) * 64 + (n ^ (e << 3));
      hh[e] = Bk_h[wi];
      ll[e] = Bk_l[wi];
    }
    h0.x = hh[0]; h0.y = hh[1]; h0.z = hh[2]; h0.w = hh[3];
    h1.x = hh[4]; h1.y = hh[5]; h1.z = hh[6]; h1.w = hh[7];
    l0.x = ll[0]; l0.y = ll[1]; l0.z = ll[2]; l0.w = ll[3];
    l1.x = ll[4]; l1.y = ll[5]; l1.z = ll[6]; l1.w = ll[7];
    const size_t oa = ((size_t)cb * DK + n) * CHUNK + tg * 8;
    *(ushort4*)&kT_h[oa]     = h0;
    *(ushort4*)&kT_h[oa + 4] = h1;
    *(ushort4*)&kT_l[oa]     = l0;
    *(ushort4*)&kT_l[oa + 4] = l1;
  }

  float4_t acc[4][2];
#pragma unroll
  for (int i = 0; i < 4; ++i)
#pragma unroll
    for (int j = 0; j < 2; ++j) acc[i][j] = (float4_t)0.0f;

#pragma unroll
  for (int ksub = 0; ksub < 2; ++ksub) {
    short8_t a_hi[4], a_lo[4], b_hi[2], b_lo[2];
#pragma unroll
    for (int i = 0; i < 4; ++i) {
      const int r = wm + i * 16 + fm;
      const int ar = r * 64 + ((ksub * 32 + fk) ^ ((r & 7) << 3));
      a_hi[i] = *(const short8_t*)&Aq_h[ar];
      a_lo[i] = *(const short8_t*)&Aq_l[ar];
    }
#pragma unroll
    for (int j = 0; j < 2; ++j) {
      const int r = wn + j * 16 + fm;
      const int br = r * 64 + ((ksub * 32 + fk) ^ ((r & 7) << 3));
      b_hi[j] = *(const short8_t*)&Bk_h[br];
      b_lo[j] = *(const short8_t*)&Bk_l[br];
    }
    __builtin_amdgcn_s_setprio(1);
#pragma unroll
    for (int i = 0; i < 4; ++i)
#pragma unroll
      for (int j = 0; j < 2; ++j) {
        acc[i][j] = __builtin_amdgcn_mfma_f32_16x16x32_bf16(a_hi[i], b_hi[j], acc[i][j], 0, 0, 0);
        acc[i][j] = __builtin_amdgcn_mfma_f32_16x16x32_bf16(a_lo[i], b_hi[j], acc[i][j], 0, 0, 0);
        acc[i][j] = __builtin_amdgcn_mfma_f32_16x16x32_bf16(a_hi[i], b_lo[j], acc[i][j], 0, 0, 0);
      }
    __builtin_amdgcn_s_setprio(0);
  }

#pragma unroll
  for (int j = 0; j < 2; ++j) {
    const int s = wn + j * 16 + fm;
#pragma unroll
    for (int i = 0; i < 4; ++i) {
#pragma unroll
      for (int r = 0; r < 4; ++r) {
        const int t = wm + i * 16 + g * 4 + r;
        const float vv = (s <= t) ? acc[i][j][r] : 0.0f;
        const unsigned short h = f2bf(vv);
        const size_t oa = ((size_t)cb * CHUNK + t) * KCAT + s;
        Acat_h[oa] = h;
        Acat_l[oa] = f2bf(vv - bf2f(h));
      }
    }
  }
}

// ---------------------------------------------------------------------------
// K3: wchunk via MFMA.  W[d][n] = (sum_t v^T[d][t]*k_t[t][n]) * pend[n].
// B-operand from kT (split-bf16, slot-swizzled gload16).  XCD-grouped grid.
// ---------------------------------------------------------------------------
__global__ __launch_bounds__(256) void wchunk_mfma_kernel(
    const unsigned short* __restrict__ Bt_h, const unsigned short* __restrict__ Bt_l,
    const unsigned short* __restrict__ kT_h, const unsigned short* __restrict__ kT_l,
    const float* __restrict__ pend, float* __restrict__ W_ws)
{
  __shared__ __align__(16) unsigned short Ah[128 * 32];  //  8 KB
  __shared__ __align__(16) unsigned short Al[128 * 32];  //  8 KB
  __shared__ __align__(16) unsigned short Kh[64 * 128];  // 16 KB
  __shared__ __align__(16) unsigned short Kl[64 * 128];  // 16 KB

  const int bd = blockIdx.x;
  const int cb = (bd >> 5) * 8 + (bd & 7);
  const int dt = (bd >> 3) & 3;
  const int tid  = threadIdx.x;
  const int wave = tid >> 6, lane = tid & 63;
  const int wm   = (wave & 1) * 64;
  const int wn   = (wave >> 1) * 32;
  const int fm   = lane & 15;
  const int fk   = (lane >> 4) * 8;

  const unsigned short* Ab_h = Bt_h + ((size_t)cb * DV + dt * 128) * CHUNK;
  const unsigned short* Ab_l = Bt_l + ((size_t)cb * DV + dt * 128) * CHUNK;
  const unsigned short* Kb_h = kT_h + (size_t)cb * DK * CHUNK;
  const unsigned short* Kb_l = kT_l + (size_t)cb * DK * CHUNK;

#pragma unroll
  for (int it = 0; it < 4; ++it) {
    const int tk = it * 256 + tid;      // 0..1023
    const int n = tk >> 4, slot = tk & 15;
    gload16(&Kb_h[(size_t)n * CHUNK + ((slot ^ (n & 15)) << 3)], &Kh[tk * 8]);
    gload16(&Kb_l[(size_t)n * CHUNK + ((slot ^ (n & 15)) << 3)], &Kl[tk * 8]);
  }

  float4_t acc[4][2];
#pragma unroll
  for (int i = 0; i < 4; ++i)
#pragma unroll
    for (int j = 0; j < 2; ++j) acc[i][j] = (float4_t)0.0f;

  for (int ks = 0; ks < 4; ++ks) {
    const int k0 = ks * 32;
#pragma unroll
    for (int q = 0; q < 2; ++q) {
      const int flat = (q * 256 + tid) * 8;
      const int row = flat >> 5, col = flat & 31;
      gload16(&Ab_h[(size_t)row * CHUNK + k0 + col], &Ah[flat]);
      gload16(&Ab_l[(size_t)row * CHUNK + k0 + col], &Al[flat]);
    }
    __syncthreads();

    short8_t a_hi[4], a_lo[4], b_hi[2], b_lo[2];
#pragma unroll
    for (int i = 0; i < 4; ++i) {
      const int ar = (wm + i * 16 + fm) * 32 + fk;
      a_hi[i] = *(const short8_t*)&Ah[ar];
      a_lo[i] = *(const short8_t*)&Al[ar];
    }
#pragma unroll
    for (int j = 0; j < 2; ++j) {
      const int n = wn + j * 16 + fm;
      const int slot = (k0 + fk) >> 3;
      const int addr = n * CHUNK + ((slot ^ (n & 15)) << 3);
      b_hi[j] = *(const short8_t*)&Kh[addr];
      b_lo[j] = *(const short8_t*)&Kl[addr];
    }
#pragma unroll
    for (int i = 0; i < 4; ++i)
#pragma unroll
      for (int j = 0; j < 2; ++j) {
        acc[i][j] = __builtin_amdgcn_mfma_f32_16x16x32_bf16(a_hi[i], b_hi[j], acc[i][j], 0, 0, 0);
        acc[i][j] = __builtin_amdgcn_mfma_f32_16x16x32_bf16(a_lo[i], b_hi[j], acc[i][j], 0, 0, 0);
        acc[i][j] = __builtin_amdgcn_mfma_f32_16x16x32_bf16(a_hi[i], b_lo[j], acc[i][j], 0, 0, 0);
      }
    __syncthreads();
  }

#pragma unroll
  for (int j = 0; j < 2; ++j) {
    const int n = wn + j * 16 + fm;
    const float pj = pend[(cb >> 2) * 256 + (cb & 3) * 64 + n];
#pragma unroll
    for (int i = 0; i < 4; ++i) {
#pragma unroll
      for (int r = 0; r < 4; ++r) {
        const int dd = dt * 128 + wm + i * 16 + (lane >> 4) * 4 + r;
        W_ws[((size_t)cb * DV + dd) * DK + n] = acc[i][j][r] * pj;
      }
    }
  }
}

// ---------------------------------------------------------------------------
// K4: sequential state scan over chunks, depth-2 software prefetch of W
// (overlaps the dependent s=s*p+w chain with the next chunks' loads).
// Emits pre-update state S_c as split-bf16 (Sh/Sl).  Bit-identical.
// ---------------------------------------------------------------------------
__global__ __launch_bounds__(256) void scan_kernel(
    const float* __restrict__ W_ws, const float* __restrict__ pend,
    unsigned short* __restrict__ Sh, unsigned short* __restrict__ Sl)
{
  const int flat = blockIdx.x * 256 + threadIdx.x;
  const int n = flat & 63;
  const int b = flat >> 15;
  float s = 0.0f;
  float w0 = W_ws[flat];
  float w1 = W_ws[131072 + flat];
  for (int c = 0; c < NCH; c += 2) {
    const float wa = w0, wb = w1;
    if (c + 2 < NCH) w0 = W_ws[(size_t)(c + 2) * 131072 + flat];
    if (c + 3 < NCH) w1 = W_ws[(size_t)(c + 3) * 131072 + flat];
    unsigned short h = f2bf(s);
    Sh[(size_t)c * 131072 + flat] = h;
    Sl[(size_t)c * 131072 + flat] = f2bf(s - bf2f(h));
    s = s * pend[c * 256 + b * 64 + n] + wa;
    h = f2bf(s);
    Sh[(size_t)(c + 1) * 131072 + flat] = h;
    Sl[(size_t)(c + 1) * 131072 + flat] = f2bf(s - bf2f(h));
    s = s * pend[(c + 1) * 256 + b * 64 + n] + wb;
  }
}

// ---------------------------------------------------------------------------
// K6: y = [A|q_t] @ [v ; S^T].  3 uniform K=64 XOR-swizzled steps.
// XCD-grouped 1D grid (4 nt-blocks of one (c,b) share an XCD's L2).
// ---------------------------------------------------------------------------
__global__ __launch_bounds__(256) void out_mfma_kernel(
    const unsigned short* __restrict__ Acat_h, const unsigned short* __restrict__ Acat_l,
    const unsigned short* __restrict__ Bt_h, const unsigned short* __restrict__ Bt_l,
    const unsigned short* __restrict__ Sh, const unsigned short* __restrict__ Sl,
    float* __restrict__ out)
{
  __shared__ __align__(16) unsigned short Ah[128 * 64];
  __shared__ __align__(16) unsigned short Al[128 * 64];
  __shared__ __align__(16) unsigned short Bh[128 * 64];
  __shared__ __align__(16) unsigned short Bl[128 * 64];

  const int bd = blockIdx.x;
  const int cb = (bd >> 5) * 8 + (bd & 7);
  const int nt = (bd >> 3) & 3;
  const int c = cb >> 2, b = cb & 3;
  const int tid  = threadIdx.x;
  const int wave = tid >> 6, lane = tid & 63;
  const int wm   = (wave & 1) * 64, wn = (wave >> 1) * 64;
  const int fm   = lane & 15;
  const int fk   = (lane >> 4) * 8;

  const unsigned short* Ab_h = Acat_h + (size_t)cb * CHUNK * KCAT;
  const unsigned short* Ab_l = Acat_l + (size_t)cb * CHUNK * KCAT;
  const unsigned short* Bb_h = Bt_h + ((size_t)cb * DV + nt * 128) * CHUNK;
  const unsigned short* Bb_l = Bt_l + ((size_t)cb * DV + nt * 128) * CHUNK;
  const unsigned short* Sb_h = Sh + ((size_t)cb * DV + nt * 128) * DK;
  const unsigned short* Sb_l = Sl + ((size_t)cb * DV + nt * 128) * DK;

  const int srow = tid >> 3;          // 0..31
  const int scolB = (tid & 7) * 16;
  const int sc = (scolB ^ ((srow & 7) << 4)) >> 1;   // halfs
  const int sdst = srow * 64 + (scolB >> 1);

  float4_t acc[4][4];
#pragma unroll
  for (int i = 0; i < 4; ++i)
#pragma unroll
    for (int j = 0; j < 4; ++j) acc[i][j] = (float4_t)0.0f;

  for (int ks = 0; ks < 3; ++ks) {
    const int k0 = ks * 64;
#pragma unroll
    for (int q = 0; q < 4; ++q) {
      const int row = q * 32 + srow;
      const int dst = q * 2048 + sdst;
      gload16(&Ab_h[(size_t)row * KCAT + k0 + sc], &Ah[dst]);
      gload16(&Ab_l[(size_t)row * KCAT + k0 + sc], &Al[dst]);
      if (ks < 2) {
        gload16(&Bb_h[(size_t)row * CHUNK + k0 + sc], &Bh[dst]);
        gload16(&Bb_l[(size_t)row * CHUNK + k0 + sc], &Bl[dst]);
      } else {
        gload16(&Sb_h[(size_t)row * DK + sc], &Bh[dst]);
        gload16(&Sb_l[(size_t)row * DK + sc], &Bl[dst]);
      }
    }
    __syncthreads();

#pragma unroll
    for (int ksub = 0; ksub < 2; ++ksub) {
      short8_t a_hi[4], a_lo[4], b_hi[4], b_lo[4];
#pragma unroll
      for (int i = 0; i < 4; ++i) {
        const int r = wm + i * 16 + fm;
        const int ar = r * 64 + ((ksub * 32 + fk) ^ ((r & 7) << 3));
        a_hi[i] = *(const short8_t*)&Ah[ar];
        a_lo[i] = *(const short8_t*)&Al[ar];
      }
#pragma unroll
      for (int j = 0; j < 4; ++j) {
        const int r = wn + j * 16 + fm;
        const int br = r * 64 + ((ksub * 32 + fk) ^ ((r & 7) << 3));
        b_hi[j] = *(const short8_t*)&Bh[br];
        b_lo[j] = *(const short8_t*)&Bl[br];
      }
      __builtin_amdgcn_s_setprio(1);
#pragma unroll
      for (int i = 0; i < 4; ++i)
#pragma unroll
        for (int j = 0; j < 4; ++j) {
          acc[i][j] = __builtin_amdgcn_mfma_f32_16x16x32_bf16(a_hi[i], b_hi[j], acc[i][j], 0, 0, 0);
          acc[i][j] = __builtin_amdgcn_mfma_f32_16x16x32_bf16(a_lo[i], b_hi[j], acc[i][j], 0, 0, 0);
          acc[i][j] = __builtin_amdgcn_mfma_f32_16x16x32_bf16(a_hi[i], b_lo[j], acc[i][j], 0, 0, 0);
        }
      __builtin_amdgcn_s_setprio(0);
    }
    __syncthreads();
  }

#pragma unroll
  for (int j = 0; j < 4; ++j) {
    const int d = nt * 128 + wn + j * 16 + fm;
#pragma unroll
    for (int i = 0; i < 4; ++i) {
#pragma unroll
      for (int r = 0; r < 4; ++r) {
        const int t = c * CHUNK + wm + i * 16 + (lane >> 4) * 4 + r;
        out[((size_t)t * B_DIM + b) * DV + d] = acc[i][j][r];
      }
    }
  }
}

// ---------------------------------------------------------------------------
extern "C" void kernel_launch(void* const* d_in, const int* in_sizes, int n_in,
                              void* d_out, int out_size, void* d_ws, size_t ws_size,
                              hipStream_t stream)
{
  const float* x  = (const float*)d_in[0];
  const float* Wv = (const float*)d_in[1];
  const float* bv = (const float*)d_in[2];
  const float* Wk = (const float*)d_in[3];
  const float* bk = (const float*)d_in[4];
  const float* Wq = (const float*)d_in[5];
  const float* bq = (const float*)d_in[6];
  const float* Wa = (const float*)d_in[7];
  const float* ba = (const float*)d_in[8];
  float* out = (float*)d_out;

  // ---- workspace layout ----
  float* ws   = (float*)d_ws;
  // Bt occupies the first 64 MB, written directly by proj.
  unsigned short* Bt_h = (unsigned short*)ws;               // 16,777,216 us
  unsigned short* Bt_l = Bt_h + (size_t)NCH * B_DIM * DV * CHUNK;
  float* k_ws = ws + (size_t)ROWS * DV;                     //  2,097,152 f (raw k)
  float* a_ws = k_ws + (size_t)ROWS * DK;                   //  2,097,152 f
  float* pend = a_ws + (size_t)ROWS * DK;                   //     16,384 f
  float* W_ws = pend + NCH * B_DIM * DK;                    //  8,388,608 f
  float* bcat = W_ws + (size_t)NCH * B_DIM * DV * DK;       //        768 f
  unsigned short* Acat_h = (unsigned short*)(bcat + NPAD);  //  6,291,456 us
  unsigned short* Acat_l = Acat_h + (size_t)NCH * B_DIM * CHUNK * KCAT;
  unsigned short* uni = Acat_l + (size_t)NCH * B_DIM * CHUNK * KCAT;
  // uni byte map: [0,32M) xh then Sh/Sl; [32M,32.75M) wh; [36M,44M) q_ws;
  // [44M,60M) kT.
  unsigned short* xh = uni;                                 // 16,777,216 us
  unsigned short* wh = xh + (size_t)ROWS * INDIM;           //    393,216 us
  float* q_ws = (float*)(uni + (size_t)18 * 1024 * 1024);   //  2,097,152 f
  unsigned short* kT_h = (unsigned short*)(q_ws + (size_t)ROWS * DK);
  unsigned short* kT_l = kT_h + (size_t)NCH * B_DIM * DK * CHUNK;
  // Sh/Sl: split-bf16 state over dead xh (written by scan, read by out)
  unsigned short* S_h = uni;                                //  8,388,608 us
  unsigned short* S_l = S_h + (size_t)NCH * B_DIM * DV * DK;

  cast_kernel<<<16384 + 384, 256, 0, stream>>>(
      x, Wv, Wk, Wq, Wa, bv, bk, bq, ba, xh, wh, bcat);
  proj_mfma_kernel<<<(ROWS / 128) * (NPAD / 128), 256, 0, stream>>>(
      xh, wh, bcat, Bt_h, Bt_l, k_ws, q_ws, a_ws);
  prep_kernel<<<NCH * B_DIM, 512, 0, stream>>>(
      a_ws, k_ws, q_ws, Acat_h, Acat_l, kT_h, kT_l, pend);
  wchunk_mfma_kernel<<<NCH * B_DIM * 4, 256, 0, stream>>>(
      Bt_h, Bt_l, kT_h, kT_l, pend, W_ws);
  scan_kernel<<<(B_DIM * DV * DK) / 256, 256, 0, stream>>>(
      W_ws, pend, S_h, S_l);
  out_mfma_kernel<<<NCH * B_DIM * 4, 256, 0, stream>>>(
      Acat_h, Acat_l, Bt_h, Bt_l, S_h, S_l, out);
}

// Round 8
// 263.645 us; speedup vs baseline: 1.0782x; 1.0111x over previous
//
#include <hip/hip_runtime.h>
#include <math.h>

#define T_DIM 8192
#define B_DIM 4
#define INDIM 512
#define DV 512
#define DK 64
#define CHUNK 128
#define NCH (T_DIM / CHUNK)     // 64
#define ROWS (T_DIM * B_DIM)    // 32768
#define NPAD 768                // 704 proj cols padded to 6x128
#define KCAT 192                // 128 intra + 64 state
#define EPSF 1e-8f

typedef float float4_t __attribute__((ext_vector_type(4)));
typedef short short8_t __attribute__((ext_vector_type(8)));
typedef _Float16 half8_t __attribute__((ext_vector_type(8)));

__device__ inline unsigned short f2bf(float f) {
  unsigned int u = __float_as_uint(f);
  unsigned int r = (u + 0x7fffu + ((u >> 16) & 1u)) >> 16;
  return (unsigned short)r;
}
__device__ inline float bf2f(unsigned short h) {
  return __uint_as_float(((unsigned int)h) << 16);
}
__device__ inline unsigned short f2h(float f) {
  _Float16 h = (_Float16)f;
  unsigned short u;
  __builtin_memcpy(&u, &h, 2);
  return u;
}

__device__ inline void gload16(const void* g, void* l) {
  __builtin_amdgcn_global_load_lds(
      (const __attribute__((address_space(1))) void*)g,
      (__attribute__((address_space(3))) void*)l, 16, 0, 0);
}

// ---------------------------------------------------------------------------
// C0: merged fp16 cast.  blocks [0,16384): x -> xh (fp16).
// blocks [16384,16768): padded concat weights -> wh (fp16) + bcat.
// ---------------------------------------------------------------------------
__global__ __launch_bounds__(256) void cast_kernel(
    const float* __restrict__ x,
    const float* __restrict__ Wv, const float* __restrict__ Wk,
    const float* __restrict__ Wq, const float* __restrict__ Wa,
    const float* __restrict__ bv, const float* __restrict__ bk,
    const float* __restrict__ bq, const float* __restrict__ ba,
    unsigned short* __restrict__ xh, unsigned short* __restrict__ wh,
    float* __restrict__ bcat)
{
  if (blockIdx.x < 16384) {
    const size_t i4 = ((size_t)blockIdx.x * 256 + threadIdx.x) * 4;
    const float4 v = *(const float4*)&x[i4];
    ushort4 h;
    h.x = f2h(v.x); h.y = f2h(v.y); h.z = f2h(v.z); h.w = f2h(v.w);
    *(ushort4*)&xh[i4] = h;
  } else {
    const int t = (blockIdx.x - 16384) * 256 + threadIdx.x;
    const size_t i4 = (size_t)t * 4;
    const int row = (int)(i4 >> 9);
    const int col = (int)(i4 & 511);
    float4 v = {0.f, 0.f, 0.f, 0.f};
    if (row < 512)      v = *(const float4*)&Wv[(size_t)row * INDIM + col];
    else if (row < 576) v = *(const float4*)&Wk[(size_t)(row - 512) * INDIM + col];
    else if (row < 640) v = *(const float4*)&Wq[(size_t)(row - 576) * INDIM + col];
    else if (row < 704) v = *(const float4*)&Wa[(size_t)(row - 640) * INDIM + col];
    ushort4 h;
    h.x = f2h(v.x); h.y = f2h(v.y); h.z = f2h(v.z); h.w = f2h(v.w);
    *(ushort4*)&wh[i4] = h;
    if (t < NPAD) {
      float b = 0.f;
      if (t < 512)      b = bv[t];
      else if (t < 576) b = bk[t - 512];
      else if (t < 640) b = bq[t - 576];
      else if (t < 704) b = ba[t - 640];
      bcat[t] = b;
    }
  }
}

// ---------------------------------------------------------------------------
// K1: fp16 MFMA projection GEMM (M=32768,K=512,N=768), fp32 accumulate.
// v-columns (xtile<4) transposed in-LDS, written directly as split-bf16
// Bt[(cb)][d][s].  3-buffer ring, depth-2 prefetch via global_load_lds,
// XCD-grouped mapping.  Round-8: Ah/Bh merged into one contiguous 48 KB
// block so the v-epilogue batches 2 bb per LDS round (syncs 9 -> 5).
// ---------------------------------------------------------------------------
__global__ __launch_bounds__(256) void proj_mfma_kernel(
    const unsigned short* __restrict__ xh, const unsigned short* __restrict__ wh,
    const float* __restrict__ bcat,
    unsigned short* __restrict__ Bt_h, unsigned short* __restrict__ Bt_l,
    float* __restrict__ k_ws, float* __restrict__ q_ws,
    float* __restrict__ a_ws)
{
  __shared__ __align__(16) _Float16 AB[2][3][128 * 32];   // 48 KB contiguous

  const int d     = blockIdx.x;
  const int grp   = d >> 3;                 // 0..191
  const int ytile = (d & 7) * 32 + grp / 6; // 0..255
  const int xtile = grp % 6;                // 0..5
  const int r0 = ytile * 128;
  const int c0 = xtile * 128;

  const int tid  = threadIdx.x;
  const int wave = tid >> 6, lane = tid & 63;
  const int wm   = (wave & 1) * 64, wn = (wave >> 1) * 64;
  const int fm   = lane & 15;
  const int fk   = (lane >> 4) * 8;
  const int g    = lane >> 4;

  float4_t acc[4][4];
#pragma unroll
  for (int i = 0; i < 4; ++i)
#pragma unroll
    for (int j = 0; j < 4; ++j) acc[i][j] = (float4_t)0.0f;

  const int srow = tid >> 2;           // 0..63
  const int scol = (tid & 3) * 8;      // 0,8,16,24

  const unsigned short* pA0 = xh + (size_t)(r0 + srow) * INDIM + scol;
  const unsigned short* pA1 = xh + (size_t)(r0 + 64 + srow) * INDIM + scol;
  const unsigned short* pB0 = wh + (size_t)(c0 + srow) * INDIM + scol;
  const unsigned short* pB1 = wh + (size_t)(c0 + 64 + srow) * INDIM + scol;

  auto stage = [&](int buf, int k0) {
    gload16(pA0 + k0, &AB[0][buf][tid * 8]);
    gload16(pA1 + k0, &AB[0][buf][(256 + tid) * 8]);
    gload16(pB0 + k0, &AB[1][buf][tid * 8]);
    gload16(pB1 + k0, &AB[1][buf][(256 + tid) * 8]);
  };

  auto compute = [&](int buf) {
    half8_t a[4], b[4];
#pragma unroll
    for (int i = 0; i < 4; ++i)
      a[i] = *(const half8_t*)&AB[0][buf][(wm + i * 16 + fm) * 32 + fk];
#pragma unroll
    for (int j = 0; j < 4; ++j)
      b[j] = *(const half8_t*)&AB[1][buf][(wn + j * 16 + fm) * 32 + fk];
    __builtin_amdgcn_s_setprio(1);
#pragma unroll
    for (int i = 0; i < 4; ++i)
#pragma unroll
      for (int j = 0; j < 4; ++j)
        acc[i][j] = __builtin_amdgcn_mfma_f32_16x16x32_f16(a[i], b[j], acc[i][j], 0, 0, 0);
    __builtin_amdgcn_s_setprio(0);
  };

  stage(0, 0);
  stage(1, 32);
  int cur = 0;
  for (int t = 0; t < 14; ++t) {
    stage((cur + 2) % 3, (t + 2) * 32);
    asm volatile("s_waitcnt vmcnt(8)" ::: "memory");
    __builtin_amdgcn_s_barrier();
    compute(cur);
    __builtin_amdgcn_s_barrier();
    cur = (cur + 1) % 3;
  }
  asm volatile("s_waitcnt vmcnt(4)" ::: "memory");
  __builtin_amdgcn_s_barrier();
  compute(cur);
  cur = (cur + 1) % 3;
  asm volatile("s_waitcnt vmcnt(0)" ::: "memory");
  __builtin_amdgcn_s_barrier();
  compute(cur);

  if (xtile < 4) {
    // ---- v path: LDS transpose -> Bt split-bf16, 2 bb per round ----
    unsigned int* Thl = (unsigned int*)&AB[0][0][0];   // 12288 words avail
    const int t0 = r0 >> 2;            // multiple of 32
    const int cb0 = (t0 >> 7) * 4;     // chunk*4
    const int s0 = t0 & 127;           // 0/32/64/96
    __syncthreads();
    for (int bb0 = 0; bb0 < 4; bb0 += 2) {
#pragma unroll
      for (int p = 0; p < 2; ++p) {
#pragma unroll
        for (int j = 0; j < 4; ++j) {
          const int d_loc = wn + j * 16 + fm;
          const float bias = bcat[c0 + d_loc];
#pragma unroll
          for (int i = 0; i < 4; ++i) {
            const int trow = (wm >> 2) + i * 4 + g;       // 0..31
            const float val = acc[i][j][bb0 + p] + bias;
            const unsigned short h = f2bf(val);
            const unsigned short l = f2bf(val - bf2f(h));
            Thl[p * 4352 + d_loc * 34 + trow] =
                (unsigned int)h | ((unsigned int)l << 16);
          }
        }
      }
      __syncthreads();
#pragma unroll
      for (int q2 = 0; q2 < 8; ++q2) {
        const int task = q2 * 256 + tid;   // 0..2047
        const int p   = task >> 10;
        const int rem = task & 1023;
        const int dd = rem >> 3;           // 0..127
        const int tq = rem & 7;            // 0..7
        const unsigned int* pw = &Thl[p * 4352 + dd * 34 + tq * 4];
        const unsigned int w0 = pw[0], w1 = pw[1], w2 = pw[2], w3 = pw[3];
        ushort4 hh, ll;
        hh.x = (unsigned short)w0; ll.x = (unsigned short)(w0 >> 16);
        hh.y = (unsigned short)w1; ll.y = (unsigned short)(w1 >> 16);
        hh.z = (unsigned short)w2; ll.z = (unsigned short)(w2 >> 16);
        hh.w = (unsigned short)w3; ll.w = (unsigned short)(w3 >> 16);
        const size_t oa = ((size_t)(cb0 + bb0 + p) * DV + c0 + dd) * CHUNK + s0 + tq * 4;
        *(ushort4*)&Bt_h[oa] = hh;
        *(ushort4*)&Bt_l[oa] = ll;
      }
      __syncthreads();
    }
  } else {
    // ---- k/q/a path: coalesced fp32 stores ----
#pragma unroll
    for (int j = 0; j < 4; ++j) {
      const int col = c0 + wn + j * 16 + fm;
      if (col >= 704) continue;
      const float bias = bcat[col];
#pragma unroll
      for (int i = 0; i < 4; ++i) {
#pragma unroll
        for (int r = 0; r < 4; ++r) {
          const int row = r0 + wm + i * 16 + g * 4 + r;  // row = t*4+b
          const float val = acc[i][j][r] + bias;
          if (col < 576) {
            k_ws[(size_t)row * DK + col - 512] = val;
          } else if (col < 640) {
            q_ws[(size_t)row * DK + col - 576] = val;
          } else {
            a_ws[(size_t)row * DK + col - 640] = 1.0f / (1.0f + expf(-val));
          }
        }
      }
    }
  }
}

// ---------------------------------------------------------------------------
// K2: fused prep+score per (c,b).  512 threads, 96 KB LDS.
// 1D XCD-grouped grid (cb on XCD cb/32).  cumprod -> q pass -> k pass ->
// kT transpose -> 8-wave score MFMA -> tril s-col write.
// ---------------------------------------------------------------------------
__global__ __launch_bounds__(512) void prep_kernel(
    const float* __restrict__ a_ws, const float* __restrict__ k_ws,
    const float* __restrict__ q_ws,
    unsigned short* __restrict__ Acat_h, unsigned short* __restrict__ Acat_l,
    unsigned short* __restrict__ kT_h, unsigned short* __restrict__ kT_l,
    float* __restrict__ pend)
{
  __shared__ float pal[CHUNK][DK];                        // 32 KB
  __shared__ __align__(16) unsigned short Aq_h[128 * 64]; // 16 KB
  __shared__ __align__(16) unsigned short Aq_l[128 * 64]; // 16 KB
  __shared__ __align__(16) unsigned short Bk_h[128 * 64]; // 16 KB
  __shared__ __align__(16) unsigned short Bk_l[128 * 64]; // 16 KB

  const int bd = blockIdx.x;                 // 0..255
  const int l  = (bd & 7) * 32 + (bd >> 3);  // XCD-grouped logical id
  const int c = l >> 2, b = l & 3;
  const int cb = c * B_DIM + b;
  const int tid = threadIdx.x;
  const int wave = tid >> 6, lane = tid & 63;
  const int wm = (wave & 1) * 64, wn = (wave >> 1) * 32;
  const int fm = lane & 15;
  const int fk = (lane >> 4) * 8;
  const int g  = lane >> 4;

#pragma unroll
  for (int i = 0; i < 4; ++i) {
    const int f = (i * 512 + tid) * 4;       // 0..8191
    const int t = f >> 6, n0 = f & 63;
    const float4 av = *(const float4*)&a_ws[(size_t)(c * CHUNK + t) * 256 + b * 64 + n0];
    *(float4*)&pal[t][n0] = av;
  }
  __syncthreads();

  if (tid < 64) {
    float p = 1.0f;
#pragma unroll 4
    for (int t = 0; t < CHUNK; ++t) {
      p *= fmaxf(pal[t][tid], EPSF);
      pal[t][tid] = p;
    }
    pend[c * 256 + b * 64 + tid] = p;
  }
  __syncthreads();

#pragma unroll
  for (int i = 0; i < 4; ++i) {
    const int f = (i * 512 + tid) * 4;
    const int t = f >> 6, n0 = f & 63;
    const float4 qv = *(const float4*)&q_ws[(size_t)(c * CHUNK + t) * 256 + b * 64 + n0];
    const size_t qa = ((size_t)cb * CHUNK + t) * KCAT + 128 + n0;
    float q0 = qv.x * pal[t][n0 + 0];
    float q1 = qv.y * pal[t][n0 + 1];
    float q2 = qv.z * pal[t][n0 + 2];
    float q3 = qv.w * pal[t][n0 + 3];
    ushort4 h, l4;
    h.x = f2bf(q0); l4.x = f2bf(q0 - bf2f(h.x));
    h.y = f2bf(q1); l4.y = f2bf(q1 - bf2f(h.y));
    h.z = f2bf(q2); l4.z = f2bf(q2 - bf2f(h.z));
    h.w = f2bf(q3); l4.w = f2bf(q3 - bf2f(h.w));
    *(ushort4*)&Acat_h[qa] = h;
    *(ushort4*)&Acat_l[qa] = l4;
    const int wi = t * 64 + (n0 ^ ((t & 7) << 3));
    *(ushort4*)&Aq_h[wi] = h;
    *(ushort4*)&Aq_l[wi] = l4;
  }

#pragma unroll
  for (int i = 0; i < 4; ++i) {
    const int f = (i * 512 + tid) * 4;
    const int t = f >> 6, n0 = f & 63;
    const float4 kv = *(const float4*)&k_ws[(size_t)(c * CHUNK + t) * 256 + b * 64 + n0];
    float k0 = kv.x / (pal[t][n0 + 0] + EPSF);
    float k1 = kv.y / (pal[t][n0 + 1] + EPSF);
    float k2 = kv.z / (pal[t][n0 + 2] + EPSF);
    float k3 = kv.w / (pal[t][n0 + 3] + EPSF);
    ushort4 h, l4;
    h.x = f2bf(k0); l4.x = f2bf(k0 - bf2f(h.x));
    h.y = f2bf(k1); l4.y = f2bf(k1 - bf2f(h.y));
    h.z = f2bf(k2); l4.z = f2bf(k2 - bf2f(h.z));
    h.w = f2bf(k3); l4.w = f2bf(k3 - bf2f(h.w));
    const int wi = t * 64 + (n0 ^ ((t & 7) << 3));
    *(ushort4*)&Bk_h[wi] = h;
    *(ushort4*)&Bk_l[wi] = l4;
  }
  __syncthreads();

#pragma unroll
  for (int it = 0; it < 2; ++it) {
    const int task = it * 512 + tid;    // 0..1023
    const int n  = task >> 4;           // 0..63
    const int tg = task & 15;           // 0..15
    ushort4 h0, h1, l0, l1;
    unsigned short hh[8], ll[8];
#pragma unroll
    for (int e = 0; e < 8; ++e) {
      const int wi = (tg * 8 + e) * 64 + (n ^ (e << 3));
      hh[e] = Bk_h[wi];
      ll[e] = Bk_l[wi];
    }
    h0.x = hh[0]; h0.y = hh[1]; h0.z = hh[2]; h0.w = hh[3];
    h1.x = hh[4]; h1.y = hh[5]; h1.z = hh[6]; h1.w = hh[7];
    l0.x = ll[0]; l0.y = ll[1]; l0.z = ll[2]; l0.w = ll[3];
    l1.x = ll[4]; l1.y = ll[5]; l1.z = ll[6]; l1.w = ll[7];
    const size_t oa = ((size_t)cb * DK + n) * CHUNK + tg * 8;
    *(ushort4*)&kT_h[oa]     = h0;
    *(ushort4*)&kT_h[oa + 4] = h1;
    *(ushort4*)&kT_l[oa]     = l0;
    *(ushort4*)&kT_l[oa + 4] = l1;
  }

  float4_t acc[4][2];
#pragma unroll
  for (int i = 0; i < 4; ++i)
#pragma unroll
    for (int j = 0; j < 2; ++j) acc[i][j] = (float4_t)0.0f;

#pragma unroll
  for (int ksub = 0; ksub < 2; ++ksub) {
    short8_t a_hi[4], a_lo[4], b_hi[2], b_lo[2];
#pragma unroll
    for (int i = 0; i < 4; ++i) {
      const int r = wm + i * 16 + fm;
      const int ar = r * 64 + ((ksub * 32 + fk) ^ ((r & 7) << 3));
      a_hi[i] = *(const short8_t*)&Aq_h[ar];
      a_lo[i] = *(const short8_t*)&Aq_l[ar];
    }
#pragma unroll
    for (int j = 0; j < 2; ++j) {
      const int r = wn + j * 16 + fm;
      const int br = r * 64 + ((ksub * 32 + fk) ^ ((r & 7) << 3));
      b_hi[j] = *(const short8_t*)&Bk_h[br];
      b_lo[j] = *(const short8_t*)&Bk_l[br];
    }
    __builtin_amdgcn_s_setprio(1);
#pragma unroll
    for (int i = 0; i < 4; ++i)
#pragma unroll
      for (int j = 0; j < 2; ++j) {
        acc[i][j] = __builtin_amdgcn_mfma_f32_16x16x32_bf16(a_hi[i], b_hi[j], acc[i][j], 0, 0, 0);
        acc[i][j] = __builtin_amdgcn_mfma_f32_16x16x32_bf16(a_lo[i], b_hi[j], acc[i][j], 0, 0, 0);
        acc[i][j] = __builtin_amdgcn_mfma_f32_16x16x32_bf16(a_hi[i], b_lo[j], acc[i][j], 0, 0, 0);
      }
    __builtin_amdgcn_s_setprio(0);
  }

#pragma unroll
  for (int j = 0; j < 2; ++j) {
    const int s = wn + j * 16 + fm;
#pragma unroll
    for (int i = 0; i < 4; ++i) {
#pragma unroll
      for (int r = 0; r < 4; ++r) {
        const int t = wm + i * 16 + g * 4 + r;
        const float vv = (s <= t) ? acc[i][j][r] : 0.0f;
        const unsigned short h = f2bf(vv);
        const size_t oa = ((size_t)cb * CHUNK + t) * KCAT + s;
        Acat_h[oa] = h;
        Acat_l[oa] = f2bf(vv - bf2f(h));
      }
    }
  }
}

// ---------------------------------------------------------------------------
// K3: wchunk via MFMA.  W[d][n] = (sum_t v^T[d][t]*k_t[t][n]) * pend[n].
// Round-8: XCD mapping aligned with prep's (cb on XCD cb/32) so kT reads
// hit the L2 that prep just wrote (1 MB/XCD working set); Bt reads align
// with proj's v-path writes too.
// ---------------------------------------------------------------------------
__global__ __launch_bounds__(256) void wchunk_mfma_kernel(
    const unsigned short* __restrict__ Bt_h, const unsigned short* __restrict__ Bt_l,
    const unsigned short* __restrict__ kT_h, const unsigned short* __restrict__ kT_l,
    const float* __restrict__ pend, float* __restrict__ W_ws)
{
  __shared__ __align__(16) unsigned short Ah[128 * 32];  //  8 KB
  __shared__ __align__(16) unsigned short Al[128 * 32];  //  8 KB
  __shared__ __align__(16) unsigned short Kh[64 * 128];  // 16 KB
  __shared__ __align__(16) unsigned short Kl[64 * 128];  // 16 KB

  const int bd = blockIdx.x;
  const int u  = (bd & 7) * 128 + (bd >> 3);   // XCD-grouped logical id
  const int cb = u >> 2;
  const int dt = u & 3;
  const int tid  = threadIdx.x;
  const int wave = tid >> 6, lane = tid & 63;
  const int wm   = (wave & 1) * 64;
  const int wn   = (wave >> 1) * 32;
  const int fm   = lane & 15;
  const int fk   = (lane >> 4) * 8;

  const unsigned short* Ab_h = Bt_h + ((size_t)cb * DV + dt * 128) * CHUNK;
  const unsigned short* Ab_l = Bt_l + ((size_t)cb * DV + dt * 128) * CHUNK;
  const unsigned short* Kb_h = kT_h + (size_t)cb * DK * CHUNK;
  const unsigned short* Kb_l = kT_l + (size_t)cb * DK * CHUNK;

#pragma unroll
  for (int it = 0; it < 4; ++it) {
    const int tk = it * 256 + tid;      // 0..1023
    const int n = tk >> 4, slot = tk & 15;
    gload16(&Kb_h[(size_t)n * CHUNK + ((slot ^ (n & 15)) << 3)], &Kh[tk * 8]);
    gload16(&Kb_l[(size_t)n * CHUNK + ((slot ^ (n & 15)) << 3)], &Kl[tk * 8]);
  }

  float4_t acc[4][2];
#pragma unroll
  for (int i = 0; i < 4; ++i)
#pragma unroll
    for (int j = 0; j < 2; ++j) acc[i][j] = (float4_t)0.0f;

  for (int ks = 0; ks < 4; ++ks) {
    const int k0 = ks * 32;
#pragma unroll
    for (int q = 0; q < 2; ++q) {
      const int flat = (q * 256 + tid) * 8;
      const int row = flat >> 5, col = flat & 31;
      gload16(&Ab_h[(size_t)row * CHUNK + k0 + col], &Ah[flat]);
      gload16(&Ab_l[(size_t)row * CHUNK + k0 + col], &Al[flat]);
    }
    __syncthreads();

    short8_t a_hi[4], a_lo[4], b_hi[2], b_lo[2];
#pragma unroll
    for (int i = 0; i < 4; ++i) {
      const int ar = (wm + i * 16 + fm) * 32 + fk;
      a_hi[i] = *(const short8_t*)&Ah[ar];
      a_lo[i] = *(const short8_t*)&Al[ar];
    }
#pragma unroll
    for (int j = 0; j < 2; ++j) {
      const int n = wn + j * 16 + fm;
      const int slot = (k0 + fk) >> 3;
      const int addr = n * CHUNK + ((slot ^ (n & 15)) << 3);
      b_hi[j] = *(const short8_t*)&Kh[addr];
      b_lo[j] = *(const short8_t*)&Kl[addr];
    }
#pragma unroll
    for (int i = 0; i < 4; ++i)
#pragma unroll
      for (int j = 0; j < 2; ++j) {
        acc[i][j] = __builtin_amdgcn_mfma_f32_16x16x32_bf16(a_hi[i], b_hi[j], acc[i][j], 0, 0, 0);
        acc[i][j] = __builtin_amdgcn_mfma_f32_16x16x32_bf16(a_lo[i], b_hi[j], acc[i][j], 0, 0, 0);
        acc[i][j] = __builtin_amdgcn_mfma_f32_16x16x32_bf16(a_hi[i], b_lo[j], acc[i][j], 0, 0, 0);
      }
    __syncthreads();
  }

#pragma unroll
  for (int j = 0; j < 2; ++j) {
    const int n = wn + j * 16 + fm;
    const float pj = pend[(cb >> 2) * 256 + (cb & 3) * 64 + n];
#pragma unroll
    for (int i = 0; i < 4; ++i) {
#pragma unroll
      for (int r = 0; r < 4; ++r) {
        const int dd = dt * 128 + wm + i * 16 + (lane >> 4) * 4 + r;
        W_ws[((size_t)cb * DV + dd) * DK + n] = acc[i][j][r] * pj;
      }
    }
  }
}

// ---------------------------------------------------------------------------
// K4: sequential state scan over chunks, depth-2 software prefetch of W.
// Emits pre-update state S_c as split-bf16 (Sh/Sl).
// ---------------------------------------------------------------------------
__global__ __launch_bounds__(256) void scan_kernel(
    const float* __restrict__ W_ws, const float* __restrict__ pend,
    unsigned short* __restrict__ Sh, unsigned short* __restrict__ Sl)
{
  const int flat = blockIdx.x * 256 + threadIdx.x;
  const int n = flat & 63;
  const int b = flat >> 15;
  float s = 0.0f;
  float w0 = W_ws[flat];
  float w1 = W_ws[131072 + flat];
  for (int c = 0; c < NCH; c += 2) {
    const float wa = w0, wb = w1;
    if (c + 2 < NCH) w0 = W_ws[(size_t)(c + 2) * 131072 + flat];
    if (c + 3 < NCH) w1 = W_ws[(size_t)(c + 3) * 131072 + flat];
    unsigned short h = f2bf(s);
    Sh[(size_t)c * 131072 + flat] = h;
    Sl[(size_t)c * 131072 + flat] = f2bf(s - bf2f(h));
    s = s * pend[c * 256 + b * 64 + n] + wa;
    h = f2bf(s);
    Sh[(size_t)(c + 1) * 131072 + flat] = h;
    Sl[(size_t)(c + 1) * 131072 + flat] = f2bf(s - bf2f(h));
    s = s * pend[(c + 1) * 256 + b * 64 + n] + wb;
  }
}

// ---------------------------------------------------------------------------
// K6: y = [A|q_t] @ [v ; S^T].  3 uniform K=64 XOR-swizzled steps.
// XCD-grouped 1D grid (4 nt-blocks of one (c,b) share an XCD's L2).
// ---------------------------------------------------------------------------
__global__ __launch_bounds__(256) void out_mfma_kernel(
    const unsigned short* __restrict__ Acat_h, const unsigned short* __restrict__ Acat_l,
    const unsigned short* __restrict__ Bt_h, const unsigned short* __restrict__ Bt_l,
    const unsigned short* __restrict__ Sh, const unsigned short* __restrict__ Sl,
    float* __restrict__ out)
{
  __shared__ __align__(16) unsigned short Ah[128 * 64];
  __shared__ __align__(16) unsigned short Al[128 * 64];
  __shared__ __align__(16) unsigned short Bh[128 * 64];
  __shared__ __align__(16) unsigned short Bl[128 * 64];

  const int bd = blockIdx.x;
  const int cb = (bd >> 5) * 8 + (bd & 7);
  const int nt = (bd >> 3) & 3;
  const int c = cb >> 2, b = cb & 3;
  const int tid  = threadIdx.x;
  const int wave = tid >> 6, lane = tid & 63;
  const int wm   = (wave & 1) * 64, wn = (wave >> 1) * 64;
  const int fm   = lane & 15;
  const int fk   = (lane >> 4) * 8;

  const unsigned short* Ab_h = Acat_h + (size_t)cb * CHUNK * KCAT;
  const unsigned short* Ab_l = Acat_l + (size_t)cb * CHUNK * KCAT;
  const unsigned short* Bb_h = Bt_h + ((size_t)cb * DV + nt * 128) * CHUNK;
  const unsigned short* Bb_l = Bt_l + ((size_t)cb * DV + nt * 128) * CHUNK;
  const unsigned short* Sb_h = Sh + ((size_t)cb * DV + nt * 128) * DK;
  const unsigned short* Sb_l = Sl + ((size_t)cb * DV + nt * 128) * DK;

  const int srow = tid >> 3;          // 0..31
  const int scolB = (tid & 7) * 16;
  const int sc = (scolB ^ ((srow & 7) << 4)) >> 1;   // halfs
  const int sdst = srow * 64 + (scolB >> 1);

  float4_t acc[4][4];
#pragma unroll
  for (int i = 0; i < 4; ++i)
#pragma unroll
    for (int j = 0; j < 4; ++j) acc[i][j] = (float4_t)0.0f;

  for (int ks = 0; ks < 3; ++ks) {
    const int k0 = ks * 64;
#pragma unroll
    for (int q = 0; q < 4; ++q) {
      const int row = q * 32 + srow;
      const int dst = q * 2048 + sdst;
      gload16(&Ab_h[(size_t)row * KCAT + k0 + sc], &Ah[dst]);
      gload16(&Ab_l[(size_t)row * KCAT + k0 + sc], &Al[dst]);
      if (ks < 2) {
        gload16(&Bb_h[(size_t)row * CHUNK + k0 + sc], &Bh[dst]);
        gload16(&Bb_l[(size_t)row * CHUNK + k0 + sc], &Bl[dst]);
      } else {
        gload16(&Sb_h[(size_t)row * DK + sc], &Bh[dst]);
        gload16(&Sb_l[(size_t)row * DK + sc], &Bl[dst]);
      }
    }
    __syncthreads();

#pragma unroll
    for (int ksub = 0; ksub < 2; ++ksub) {
      short8_t a_hi[4], a_lo[4], b_hi[4], b_lo[4];
#pragma unroll
      for (int i = 0; i < 4; ++i) {
        const int r = wm + i * 16 + fm;
        const int ar = r * 64 + ((ksub * 32 + fk) ^ ((r & 7) << 3));
        a_hi[i] = *(const short8_t*)&Ah[ar];
        a_lo[i] = *(const short8_t*)&Al[ar];
      }
#pragma unroll
      for (int j = 0; j < 4; ++j) {
        const int r = wn + j * 16 + fm;
        const int br = r * 64 + ((ksub * 32 + fk) ^ ((r & 7) << 3));
        b_hi[j] = *(const short8_t*)&Bh[br];
        b_lo[j] = *(const short8_t*)&Bl[br];
      }
      __builtin_amdgcn_s_setprio(1);
#pragma unroll
      for (int i = 0; i < 4; ++i)
#pragma unroll
        for (int j = 0; j < 4; ++j) {
          acc[i][j] = __builtin_amdgcn_mfma_f32_16x16x32_bf16(a_hi[i], b_hi[j], acc[i][j], 0, 0, 0);
          acc[i][j] = __builtin_amdgcn_mfma_f32_16x16x32_bf16(a_lo[i], b_hi[j], acc[i][j], 0, 0, 0);
          acc[i][j] = __builtin_amdgcn_mfma_f32_16x16x32_bf16(a_hi[i], b_lo[j], acc[i][j], 0, 0, 0);
        }
      __builtin_amdgcn_s_setprio(0);
    }
    __syncthreads();
  }

#pragma unroll
  for (int j = 0; j < 4; ++j) {
    const int d = nt * 128 + wn + j * 16 + fm;
#pragma unroll
    for (int i = 0; i < 4; ++i) {
#pragma unroll
      for (int r = 0; r < 4; ++r) {
        const int t = c * CHUNK + wm + i * 16 + (lane >> 4) * 4 + r;
        out[((size_t)t * B_DIM + b) * DV + d] = acc[i][j][r];
      }
    }
  }
}

// ---------------------------------------------------------------------------
extern "C" void kernel_launch(void* const* d_in, const int* in_sizes, int n_in,
                              void* d_out, int out_size, void* d_ws, size_t ws_size,
                              hipStream_t stream)
{
  const float* x  = (const float*)d_in[0];
  const float* Wv = (const float*)d_in[1];
  const float* bv = (const float*)d_in[2];
  const float* Wk = (const float*)d_in[3];
  const float* bk = (const float*)d_in[4];
  const float* Wq = (const float*)d_in[5];
  const float* bq = (const float*)d_in[6];
  const float* Wa = (const float*)d_in[7];
  const float* ba = (const float*)d_in[8];
  float* out = (float*)d_out;

  // ---- workspace layout ----
  float* ws   = (float*)d_ws;
  // Bt occupies the first 64 MB, written directly by proj.
  unsigned short* Bt_h = (unsigned short*)ws;               // 16,777,216 us
  unsigned short* Bt_l = Bt_h + (size_t)NCH * B_DIM * DV * CHUNK;
  float* k_ws = ws + (size_t)ROWS * DV;                     //  2,097,152 f (raw k)
  float* a_ws = k_ws + (size_t)ROWS * DK;                   //  2,097,152 f
  float* pend = a_ws + (size_t)ROWS * DK;                   //     16,384 f
  float* W_ws = pend + NCH * B_DIM * DK;                    //  8,388,608 f
  float* bcat = W_ws + (size_t)NCH * B_DIM * DV * DK;       //        768 f
  unsigned short* Acat_h = (unsigned short*)(bcat + NPAD);  //  6,291,456 us
  unsigned short* Acat_l = Acat_h + (size_t)NCH * B_DIM * CHUNK * KCAT;
  unsigned short* uni = Acat_l + (size_t)NCH * B_DIM * CHUNK * KCAT;
  // uni byte map: [0,32M) xh then Sh/Sl; [32M,32.75M) wh; [36M,44M) q_ws;
  // [44M,60M) kT.
  unsigned short* xh = uni;                                 // 16,777,216 us
  unsigned short* wh = xh + (size_t)ROWS * INDIM;           //    393,216 us
  float* q_ws = (float*)(uni + (size_t)18 * 1024 * 1024);   //  2,097,152 f
  unsigned short* kT_h = (unsigned short*)(q_ws + (size_t)ROWS * DK);
  unsigned short* kT_l = kT_h + (size_t)NCH * B_DIM * DK * CHUNK;
  // Sh/Sl: split-bf16 state over dead xh (written by scan, read by out)
  unsigned short* S_h = uni;                                //  8,388,608 us
  unsigned short* S_l = S_h + (size_t)NCH * B_DIM * DV * DK;

  cast_kernel<<<16384 + 384, 256, 0, stream>>>(
      x, Wv, Wk, Wq, Wa, bv, bk, bq, ba, xh, wh, bcat);
  proj_mfma_kernel<<<(ROWS / 128) * (NPAD / 128), 256, 0, stream>>>(
      xh, wh, bcat, Bt_h, Bt_l, k_ws, q_ws, a_ws);
  prep_kernel<<<NCH * B_DIM, 512, 0, stream>>>(
      a_ws, k_ws, q_ws, Acat_h, Acat_l, kT_h, kT_l, pend);
  wchunk_mfma_kernel<<<NCH * B_DIM * 4, 256, 0, stream>>>(
      Bt_h, Bt_l, kT_h, kT_l, pend, W_ws);
  scan_kernel<<<(B_DIM * DV * DK) / 256, 256, 0, stream>>>(
      W_ws, pend, S_h, S_l);
  out_mfma_kernel<<<NCH * B_DIM * 4, 256, 0, stream>>>(
      Acat_h, Acat_l, Bt_h, Bt_l, S_h, S_l, out);
}